// Round 1
// baseline (3409.966 us; speedup 1.0000x reference)
//
#include <hip/hip_runtime.h>
#include <math.h>

// ---------------- problem constants ----------------
constexpr int CB  = 2;
constexpr int CL  = 28 * 28 * 28;   // 21952
constexpr int CC  = 192;
constexpr int CN  = 343;            // 7^3 tokens per window
constexpr int CNH = 6;
constexpr int CM  = CB * CL;        // 43904 total tokens (= 128 windows * 343)
constexpr int POOL_CHUNKS = 86;     // ceil(21952/256)

// ---------------- workspace layout (floats) ----------------
constexpr size_t OFF_XN   = 0;                       // 8,429,568
constexpr size_t OFF_YN   = 8429568;                 // 8,429,568
constexpr size_t OFF_Q    = 16859136;                // 8,429,568
constexpr size_t OFF_K    = 25288704;                // 8,429,568
constexpr size_t OFF_V    = 33718272;                // 8,429,568
constexpr size_t OFF_H1   = 42147840;                // 2,809,856 (B,L,64)
constexpr size_t OFF_H2   = 44957696;                // 8,429,568
constexpr size_t OFF_XOUT = 53387264;                // 8,429,568
constexpr size_t OFF_A    = 61816832;                // 384 (+pad)
constexpr size_t OFF_PART = 61817344;                // 2*86*192 = 33,024
constexpr size_t OFF_W1R  = 61850368;                // 331,776
constexpr size_t OFF_W2R  = 62182144;                // 331,776 -> total 62,513,920 fl (~250MB)
// aliases (lifetimes verified: conv1 reads XN before attn writes; gemm_kv reads YN
// before LN2 writes; attention+proj+pool read Q/K/V/H1/H2 before fc1 writes HID)
constexpr size_t OFF_ATTN = OFF_XN;
constexpr size_t OFF_HLN  = OFF_YN;
constexpr size_t OFF_HID  = OFF_Q;                   // 33,718,272 floats, ends before XOUT

// window token id -> (batch, spatial pos)
__device__ __forceinline__ int tt_to_pos(int tt, int& b) {
  int bw = tt / 343;
  int n  = tt - bw * 343;
  b = bw >> 6;
  int wi = bw & 63;
  int n0 = n / 49, r = n - n0 * 49;
  int n1 = r / 7,  n2 = r - n1 * 7;
  int h = (wi >> 4) * 7 + n0;
  int w = ((wi >> 2) & 3) * 7 + n1;
  int t = (wi & 3) * 7 + n2;
  return (h * 28 + w) * 28 + t;
}

__device__ __forceinline__ void st4(float (&S)[64][17], int r, int c0, float4 v) {
  S[r][c0 + 0] = v.x; S[r][c0 + 1] = v.y; S[r][c0 + 2] = v.z; S[r][c0 + 3] = v.w;
}

__device__ __forceinline__ void mm16(const float (&As)[64][17], const float (&Bs)[64][17],
                                     int ty4, int tx4, float (&acc)[4][4]) {
#pragma unroll
  for (int kk = 0; kk < 16; ++kk) {
    float a0 = As[ty4 + 0][kk], a1 = As[ty4 + 1][kk], a2 = As[ty4 + 2][kk], a3 = As[ty4 + 3][kk];
    float b0 = Bs[tx4 + 0][kk], b1 = Bs[tx4 + 1][kk], b2 = Bs[tx4 + 2][kk], b3 = Bs[tx4 + 3][kk];
    acc[0][0] += a0 * b0; acc[0][1] += a0 * b1; acc[0][2] += a0 * b2; acc[0][3] += a0 * b3;
    acc[1][0] += a1 * b0; acc[1][1] += a1 * b1; acc[1][2] += a1 * b2; acc[1][3] += a1 * b3;
    acc[2][0] += a2 * b0; acc[2][1] += a2 * b1; acc[2][2] += a2 * b2; acc[2][3] += a2 * b3;
    acc[3][0] += a3 * b0; acc[3][1] += a3 * b1; acc[3][2] += a3 * b2; acc[3][3] += a3 * b3;
  }
}

__device__ __forceinline__ float gelu_exact(float x) {
  return 0.5f * x * (1.0f + erff(x * 0.70710678118654752f));
}

// ---------------- LayerNorm over C=192 (one wave per row) ----------------
__global__ __launch_bounds__(256) void ln_kernel(const float* __restrict__ in,
                                                 const float* __restrict__ g,
                                                 const float* __restrict__ bb,
                                                 float* __restrict__ out, int nrows) {
  int wave = threadIdx.x >> 6;
  int lane = threadIdx.x & 63;
  int row = blockIdx.x * 4 + wave;
  if (row >= nrows) return;
  const float* p = in + (size_t)row * CC;
  float v0 = p[lane], v1 = p[lane + 64], v2 = p[lane + 128];
  float s = v0 + v1 + v2;
  for (int o = 32; o; o >>= 1) s += __shfl_xor(s, o, 64);
  float mean = s * (1.0f / 192.0f);
  float d0 = v0 - mean, d1 = v1 - mean, d2 = v2 - mean;
  float qs = d0 * d0 + d1 * d1 + d2 * d2;
  for (int o = 32; o; o >>= 1) qs += __shfl_xor(qs, o, 64);
  float rs = rsqrtf(qs * (1.0f / 192.0f) + 1e-5f);
  float* po = out + (size_t)row * CC;
  po[lane]        = d0 * rs * g[lane]        + bb[lane];
  po[lane + 64]   = d1 * rs * g[lane + 64]   + bb[lane + 64];
  po[lane + 128]  = d2 * rs * g[lane + 128]  + bb[lane + 128];
}

// ---------------- conv weight re-layout: (O,I,27) -> (O, tap*CIN + i) ----------------
__global__ void wtr1_kernel(const float* __restrict__ w, float* __restrict__ wr) {
  int idx = blockIdx.x * 256 + threadIdx.x;
  if (idx >= 64 * 5184) return;
  int o = idx / 5184, r = idx - o * 5184;
  int tap = r / 192, i = r - tap * 192;
  wr[idx] = w[o * 5184 + i * 27 + tap];
}
__global__ void wtr2_kernel(const float* __restrict__ w, float* __restrict__ wr) {
  int idx = blockIdx.x * 256 + threadIdx.x;
  if (idx >= 192 * 1728) return;
  int o = idx / 1728, r = idx - o * 1728;
  int tap = r / 64, i = r - tap * 64;
  wr[idx] = w[o * 1728 + i * 27 + tap];
}

// ---------------- Q projection (windowed rows) ----------------
__global__ __launch_bounds__(256) void gemm_q_kernel(const float* __restrict__ xn,
                                                     const float* __restrict__ qkvw,
                                                     const float* __restrict__ qkvb,
                                                     float* __restrict__ qout) {
  __shared__ float As[64][17];
  __shared__ float Bs[64][17];
  const int tid = threadIdx.x;
  const int lr = tid >> 2, lk = (tid & 3) * 4;
  const int ty4 = (tid >> 4) << 2, tx4 = (tid & 15) << 2;
  int bq;
  const int pos = tt_to_pos(blockIdx.x * 64 + lr, bq);
  const float* arow = xn + ((size_t)bq * CL + pos) * CC + lk;
  const int jb = blockIdx.y * 64;
  const float* brow = qkvw + (size_t)(jb + lr) * CC + lk;
  float acc[4][4] = {};
  for (int k0 = 0; k0 < CC; k0 += 16) {
    float4 av = *(const float4*)(arow + k0);
    float4 bv = *(const float4*)(brow + k0);
    st4(As, lr, lk, av); st4(Bs, lr, lk, bv);
    __syncthreads();
    mm16(As, Bs, ty4, tx4, acc);
    __syncthreads();
  }
#pragma unroll
  for (int i = 0; i < 4; ++i) {
    int tt = blockIdx.x * 64 + ty4 + i;
    int bw = tt / 343, n = tt - bw * 343;
#pragma unroll
    for (int j = 0; j < 4; ++j) {
      int jj = jb + tx4 + j;
      int head = jj >> 5, d = jj & 31;
      qout[(((size_t)bw * 6 + head) * 343 + n) * 32 + d] =
          (acc[i][j] + qkvb[jj]) * 0.17677669529663687f;
    }
  }
}

// ---------------- K,V projection (windowed rows, from yn) ----------------
__global__ __launch_bounds__(256) void gemm_kv_kernel(const float* __restrict__ yn,
                                                      const float* __restrict__ qkvw,
                                                      const float* __restrict__ qkvb,
                                                      float* __restrict__ kout,
                                                      float* __restrict__ vout) {
  __shared__ float As[64][17];
  __shared__ float Bs[64][17];
  const int tid = threadIdx.x;
  const int lr = tid >> 2, lk = (tid & 3) * 4;
  const int ty4 = (tid >> 4) << 2, tx4 = (tid & 15) << 2;
  int bq;
  const int pos = tt_to_pos(blockIdx.x * 64 + lr, bq);
  const float* arow = yn + ((size_t)bq * CL + pos) * CC + lk;
  const int jb = blockIdx.y * 64;
  const float* brow = qkvw + (size_t)(192 + jb + lr) * CC + lk;
  float acc[4][4] = {};
  for (int k0 = 0; k0 < CC; k0 += 16) {
    float4 av = *(const float4*)(arow + k0);
    float4 bv = *(const float4*)(brow + k0);
    st4(As, lr, lk, av); st4(Bs, lr, lk, bv);
    __syncthreads();
    mm16(As, Bs, ty4, tx4, acc);
    __syncthreads();
  }
#pragma unroll
  for (int i = 0; i < 4; ++i) {
    int tt = blockIdx.x * 64 + ty4 + i;
    int bw = tt / 343, n = tt - bw * 343;
#pragma unroll
    for (int j = 0; j < 4; ++j) {
      int jj = jb + tx4 + j;
      float val = acc[i][j] + qkvb[192 + jj];
      int jv = (jj < 192) ? jj : jj - 192;
      int head = jv >> 5, d = jv & 31;
      float* dst = (jj < 192) ? kout : vout;
      dst[(((size_t)bw * 6 + head) * 343 + n) * 32 + d] = val;
    }
  }
}

// ---------------- implicit-GEMM 3x3x3 conv (pad 1), optional exact-GELU ----------------
__global__ __launch_bounds__(256) void conv_gemm_kernel(const float* __restrict__ src,
                                                        const float* __restrict__ wr,
                                                        const float* __restrict__ bias,
                                                        float* __restrict__ dst,
                                                        int CIN, int COUT, int KT, int do_gelu) {
  __shared__ float As[64][17];
  __shared__ float Bs[64][17];
  const int tid = threadIdx.x;
  const int lr = tid >> 2, lk = (tid & 3) * 4;
  const int ty4 = (tid >> 4) << 2, tx4 = (tid & 15) << 2;
  const int row = blockIdx.x * 64 + lr;
  const int b   = row / CL;
  const int pos = row - b * CL;
  const int h   = pos / 784;
  const int w   = (pos / 28) % 28;
  const int t   = pos % 28;
  const int jb  = blockIdx.y * 64;
  const float* brow = wr + (size_t)(jb + lr) * KT + lk;
  float acc[4][4] = {};
  int tap = 0, cbase = 0;
  for (int k0 = 0; k0 < KT; k0 += 16) {
    int dh = tap / 9 - 1;
    int dw = (tap / 3) % 3 - 1;
    int dt = tap % 3 - 1;
    int hh = h + dh, ww = w + dw, t2 = t + dt;
    bool ok = ((unsigned)hh < 28u) && ((unsigned)ww < 28u) && ((unsigned)t2 < 28u);
    float4 av = make_float4(0.f, 0.f, 0.f, 0.f);
    if (ok) av = *(const float4*)(src + ((size_t)b * CL + (hh * 28 + ww) * 28 + t2) * CIN + cbase + lk);
    float4 bv = *(const float4*)(brow + k0);
    st4(As, lr, lk, av); st4(Bs, lr, lk, bv);
    __syncthreads();
    mm16(As, Bs, ty4, tx4, acc);
    __syncthreads();
    cbase += 16;
    if (cbase == CIN) { cbase = 0; ++tap; }
  }
#pragma unroll
  for (int i = 0; i < 4; ++i) {
    int r = blockIdx.x * 64 + ty4 + i;
#pragma unroll
    for (int j = 0; j < 4; ++j) {
      int jj = jb + tx4 + j;
      float v = acc[i][j] + bias[jj];
      if (do_gelu) v = gelu_exact(v);
      dst[(size_t)r * COUT + jj] = v;
    }
  }
}

// ---------------- spatial mean partial sums ----------------
__global__ __launch_bounds__(192) void pool1_kernel(const float* __restrict__ h2,
                                                    float* __restrict__ part) {
  int c = threadIdx.x;
  int chunk = blockIdx.x;
  int b = blockIdx.y;
  int l0 = chunk * 256;
  int cnt = CL - l0; if (cnt > 256) cnt = 256;
  const float* p = h2 + ((size_t)b * CL + l0) * CC + c;
  float s = 0.0f;
  for (int i = 0; i < cnt; ++i) s += p[(size_t)i * CC];
  part[((size_t)b * POOL_CHUNKS + chunk) * CC + c] = s;
}

// ---------------- channel attention (relu fc 192->12, sigmoid fc 12->192) ----------------
__global__ __launch_bounds__(192) void ca_kernel(const float* __restrict__ part,
                                                 const float* __restrict__ ca1w,
                                                 const float* __restrict__ ca1b,
                                                 const float* __restrict__ ca2w,
                                                 const float* __restrict__ ca2b,
                                                 float* __restrict__ av) {
  __shared__ float pl[192];
  __shared__ float hid[12];
  int c = threadIdx.x, b = blockIdx.x;
  float s = 0.0f;
  for (int ch = 0; ch < POOL_CHUNKS; ++ch) s += part[((size_t)b * POOL_CHUNKS + ch) * CC + c];
  pl[c] = s * (1.0f / (float)CL);
  __syncthreads();
  if (c < 12) {
    float t = ca1b[c];
    for (int i = 0; i < 192; ++i) t += ca1w[c * 192 + i] * pl[i];
    hid[c] = fmaxf(t, 0.0f);
  }
  __syncthreads();
  float t = ca2b[c];
#pragma unroll
  for (int j = 0; j < 12; ++j) t += ca2w[c * 12 + j] * hid[j];
  av[b * 192 + c] = 1.0f / (1.0f + __expf(-t));
}

// ---------------- fused window attention: QK^T + rpb + softmax + PV ----------------
__global__ __launch_bounds__(256) void attn_kernel(const float* __restrict__ q,
                                                   const float* __restrict__ k,
                                                   const float* __restrict__ v,
                                                   const float* __restrict__ rpb,
                                                   float* __restrict__ aout) {
  __shared__ float kl[343][33];
  __shared__ float vl[343][32];
  __shared__ float ql[32][33];
  __shared__ float sc[32][344];
  __shared__ float rinv[32];
  const int tid = threadIdx.x;
  const int wh = blockIdx.x;              // bw*6 + head
  const int bw = wh / 6, head = wh - bw * 6;
  const int q0 = blockIdx.y * 32;
  const int nq = (343 - q0 < 32) ? (343 - q0) : 32;
  const float* kp = k + (size_t)wh * 343 * 32;
  const float* vp = v + (size_t)wh * 343 * 32;
  const float* qp = q + (size_t)wh * 343 * 32;
  for (int idx = tid; idx < 343 * 32; idx += 256) {
    int n = idx >> 5, d = idx & 31;
    kl[n][d] = kp[idx];
    vl[n][d] = vp[idx];
  }
  for (int idx = tid; idx < 32 * 32; idx += 256) {
    int n = idx >> 5, d = idx & 31;
    ql[n][d] = (q0 + n < 343) ? qp[(size_t)(q0 + n) * 32 + d] : 0.0f;
  }
  __syncthreads();
  // scores + relative position bias
  for (int p = tid; p < 32 * 343; p += 256) {
    int qi = p / 343, kj = p - qi * 343;
    float s = 0.0f;
#pragma unroll
    for (int d = 0; d < 32; ++d) s += ql[qi][d] * kl[kj][d];
    int ng = q0 + qi; if (ng > 342) ng = 342;
    int a0 = ng / 49, ra = ng - a0 * 49; int a1 = ra / 7, a2 = ra - a1 * 7;
    int b0 = kj / 49, rb = kj - b0 * 49; int b1 = rb / 7, b2 = rb - b1 * 7;
    int ridx = ((a0 - b0 + 6) * 13 + (a1 - b1 + 6)) * 13 + (a2 - b2 + 6);
    sc[qi][kj] = s + rpb[ridx * 6 + head];
  }
  __syncthreads();
  // softmax over kj per row (8 lanes per row)
  {
    int r = tid >> 3, l8 = tid & 7;
    float m = -1e30f;
    for (int j = l8; j < 343; j += 8) m = fmaxf(m, sc[r][j]);
    m = fmaxf(m, __shfl_xor(m, 1, 64));
    m = fmaxf(m, __shfl_xor(m, 2, 64));
    m = fmaxf(m, __shfl_xor(m, 4, 64));
    float sum = 0.0f;
    for (int j = l8; j < 343; j += 8) {
      float e = __expf(sc[r][j] - m);
      sc[r][j] = e;
      sum += e;
    }
    sum += __shfl_xor(sum, 1, 64);
    sum += __shfl_xor(sum, 2, 64);
    sum += __shfl_xor(sum, 4, 64);
    if (l8 == 0) rinv[r] = 1.0f / sum;
  }
  __syncthreads();
  // PV
  {
    int qi = tid >> 3, d0 = (tid & 7) << 2;
    float o0 = 0, o1 = 0, o2 = 0, o3 = 0;
    for (int kj = 0; kj < 343; ++kj) {
      float pv = sc[qi][kj];
      o0 += pv * vl[kj][d0 + 0];
      o1 += pv * vl[kj][d0 + 1];
      o2 += pv * vl[kj][d0 + 2];
      o3 += pv * vl[kj][d0 + 3];
    }
    if (qi < nq) {
      float inv = rinv[qi];
      float* op = aout + ((size_t)bw * 343 + q0 + qi) * CC + head * 32 + d0;
      op[0] = o0 * inv; op[1] = o1 * inv; op[2] = o2 * inv; op[3] = o3 * inv;
    }
  }
}

// ---------------- proj + window-reverse + 3-way residual ----------------
__global__ __launch_bounds__(256) void proj_kernel(const float* __restrict__ attnr,
                                                   const float* __restrict__ projw,
                                                   const float* __restrict__ projb,
                                                   const float* __restrict__ x0,
                                                   const float* __restrict__ h2,
                                                   const float* __restrict__ cav,
                                                   float* __restrict__ xout) {
  __shared__ float As[64][17];
  __shared__ float Bs[64][17];
  const int tid = threadIdx.x;
  const int lr = tid >> 2, lk = (tid & 3) * 4;
  const int ty4 = (tid >> 4) << 2, tx4 = (tid & 15) << 2;
  const float* arow = attnr + (size_t)(blockIdx.x * 64 + lr) * CC + lk;
  const int jb = blockIdx.y * 64;
  const float* brow = projw + (size_t)(jb + lr) * CC + lk;
  float acc[4][4] = {};
  for (int k0 = 0; k0 < CC; k0 += 16) {
    float4 av = *(const float4*)(arow + k0);
    float4 bv = *(const float4*)(brow + k0);
    st4(As, lr, lk, av); st4(Bs, lr, lk, bv);
    __syncthreads();
    mm16(As, Bs, ty4, tx4, acc);
    __syncthreads();
  }
#pragma unroll
  for (int i = 0; i < 4; ++i) {
    int tt = blockIdx.x * 64 + ty4 + i;
    int bq;
    int pos = tt_to_pos(tt, bq);
    size_t base = ((size_t)bq * CL + pos) * CC;
#pragma unroll
    for (int j = 0; j < 4; ++j) {
      int jj = jb + tx4 + j;
      size_t addr = base + jj;
      xout[addr] = x0[addr] + acc[i][j] + projb[jj] + h2[addr] * cav[bq * 192 + jj];
    }
  }
}

// ---------------- MLP fc1 (+exact GELU) ----------------
__global__ __launch_bounds__(256) void fc1_kernel(const float* __restrict__ hln,
                                                  const float* __restrict__ fc1w,
                                                  const float* __restrict__ fc1b,
                                                  float* __restrict__ hid) {
  __shared__ float As[64][17];
  __shared__ float Bs[64][17];
  const int tid = threadIdx.x;
  const int lr = tid >> 2, lk = (tid & 3) * 4;
  const int ty4 = (tid >> 4) << 2, tx4 = (tid & 15) << 2;
  const float* arow = hln + (size_t)(blockIdx.x * 64 + lr) * CC + lk;
  const int jb = blockIdx.y * 64;
  const float* brow = fc1w + (size_t)(jb + lr) * CC + lk;
  float acc[4][4] = {};
  for (int k0 = 0; k0 < CC; k0 += 16) {
    float4 av = *(const float4*)(arow + k0);
    float4 bv = *(const float4*)(brow + k0);
    st4(As, lr, lk, av); st4(Bs, lr, lk, bv);
    __syncthreads();
    mm16(As, Bs, ty4, tx4, acc);
    __syncthreads();
  }
#pragma unroll
  for (int i = 0; i < 4; ++i) {
    int r = blockIdx.x * 64 + ty4 + i;
#pragma unroll
    for (int j = 0; j < 4; ++j) {
      int jj = jb + tx4 + j;
      hid[(size_t)r * 768 + jj] = gelu_exact(acc[i][j] + fc1b[jj]);
    }
  }
}

// ---------------- MLP fc2 + final residual -> d_out ----------------
__global__ __launch_bounds__(256) void fc2_kernel(const float* __restrict__ hid,
                                                  const float* __restrict__ fc2w,
                                                  const float* __restrict__ fc2b,
                                                  const float* __restrict__ xout,
                                                  float* __restrict__ out) {
  __shared__ float As[64][17];
  __shared__ float Bs[64][17];
  const int tid = threadIdx.x;
  const int lr = tid >> 2, lk = (tid & 3) * 4;
  const int ty4 = (tid >> 4) << 2, tx4 = (tid & 15) << 2;
  const float* arow = hid + (size_t)(blockIdx.x * 64 + lr) * 768 + lk;
  const int jb = blockIdx.y * 64;
  const float* brow = fc2w + (size_t)(jb + lr) * 768 + lk;
  float acc[4][4] = {};
  for (int k0 = 0; k0 < 768; k0 += 16) {
    float4 av = *(const float4*)(arow + k0);
    float4 bv = *(const float4*)(brow + k0);
    st4(As, lr, lk, av); st4(Bs, lr, lk, bv);
    __syncthreads();
    mm16(As, Bs, ty4, tx4, acc);
    __syncthreads();
  }
#pragma unroll
  for (int i = 0; i < 4; ++i) {
    int r = blockIdx.x * 64 + ty4 + i;
#pragma unroll
    for (int j = 0; j < 4; ++j) {
      int jj = jb + tx4 + j;
      size_t addr = (size_t)r * CC + jj;
      out[addr] = xout[addr] + acc[i][j] + fc2b[jj];
    }
  }
}

// ---------------- launch ----------------
extern "C" void kernel_launch(void* const* d_in, const int* in_sizes, int n_in,
                              void* d_out, int out_size, void* d_ws, size_t ws_size,
                              hipStream_t stream) {
  const float* x     = (const float*)d_in[0];
  const float* y     = (const float*)d_in[1];
  // d_in[2] mask_matrix unused (shift_size == 0)
  const float* n1g   = (const float*)d_in[3];
  const float* n1b   = (const float*)d_in[4];
  const float* qkvw  = (const float*)d_in[5];
  const float* qkvb  = (const float*)d_in[6];
  const float* projw = (const float*)d_in[7];
  const float* projb = (const float*)d_in[8];
  const float* rpb   = (const float*)d_in[9];
  const float* n2g   = (const float*)d_in[10];
  const float* n2b   = (const float*)d_in[11];
  const float* fc1w  = (const float*)d_in[12];
  const float* fc1b  = (const float*)d_in[13];
  const float* fc2w  = (const float*)d_in[14];
  const float* fc2b  = (const float*)d_in[15];
  const float* w1    = (const float*)d_in[16];
  const float* b1    = (const float*)d_in[17];
  const float* w2    = (const float*)d_in[18];
  const float* b2    = (const float*)d_in[19];
  const float* ca1w  = (const float*)d_in[20];
  const float* ca1b  = (const float*)d_in[21];
  const float* ca2w  = (const float*)d_in[22];
  const float* ca2b  = (const float*)d_in[23];

  float* ws  = (float*)d_ws;
  float* out = (float*)d_out;

  float* xn    = ws + OFF_XN;
  float* yn    = ws + OFF_YN;
  float* qb    = ws + OFF_Q;
  float* kb    = ws + OFF_K;
  float* vb    = ws + OFF_V;
  float* h1    = ws + OFF_H1;
  float* h2    = ws + OFF_H2;
  float* xo    = ws + OFF_XOUT;
  float* av    = ws + OFF_A;
  float* part  = ws + OFF_PART;
  float* w1r   = ws + OFF_W1R;
  float* w2r   = ws + OFF_W2R;
  float* attnr = ws + OFF_ATTN;
  float* hln   = ws + OFF_HLN;
  float* hid   = ws + OFF_HID;

  // 1. LayerNorm1 on x and y
  ln_kernel<<<CM / 4, 256, 0, stream>>>(x, n1g, n1b, xn, CM);
  ln_kernel<<<CM / 4, 256, 0, stream>>>(y, n1g, n1b, yn, CM);

  // conv weight re-layout
  wtr1_kernel<<<(64 * 5184 + 255) / 256, 256, 0, stream>>>(w1, w1r);
  wtr2_kernel<<<(192 * 1728 + 255) / 256, 256, 0, stream>>>(w2, w2r);

  // 2. QKV projections (windowed rows)
  gemm_q_kernel<<<dim3(CM / 64, 3), 256, 0, stream>>>(xn, qkvw, qkvb, qb);
  gemm_kv_kernel<<<dim3(CM / 64, 6), 256, 0, stream>>>(yn, qkvw, qkvb, kb, vb);

  // 3. CAB convs (implicit GEMM)
  conv_gemm_kernel<<<dim3(CM / 64, 1), 256, 0, stream>>>(xn, w1r, b1, h1, 192, 64, 5184, 1);
  conv_gemm_kernel<<<dim3(CM / 64, 3), 256, 0, stream>>>(h1, w2r, b2, h2, 64, 192, 1728, 0);

  // 4. channel attention
  pool1_kernel<<<dim3(POOL_CHUNKS, CB), 192, 0, stream>>>(h2, part);
  ca_kernel<<<CB, 192, 0, stream>>>(part, ca1w, ca1b, ca2w, ca2b, av);

  // 5. fused window attention (writes attnr, aliases xn)
  attn_kernel<<<dim3(128 * 6, 11), 256, 0, stream>>>(qb, kb, vb, rpb, attnr);

  // 6. proj + window reverse + residual (x + attn + conv*ca)
  proj_kernel<<<dim3(CM / 64, 3), 256, 0, stream>>>(attnr, projw, projb, x, h2, av, xo);

  // 7. LayerNorm2 (writes hln, aliases yn)
  ln_kernel<<<CM / 4, 256, 0, stream>>>(xo, n2g, n2b, hln, CM);

  // 8. MLP
  fc1_kernel<<<dim3(CM / 64, 12), 256, 0, stream>>>(hln, fc1w, fc1b, hid);
  fc2_kernel<<<dim3(CM / 64, 3), 256, 0, stream>>>(hid, fc2w, fc2b, xo, out);
}

// Round 3
// 1438.010 us; speedup vs baseline: 2.3713x; 2.3713x over previous
//
#include <hip/hip_runtime.h>
#include <math.h>

// ---------------- problem constants ----------------
constexpr int CB  = 2;
constexpr int CL  = 28 * 28 * 28;   // 21952
constexpr int CC  = 192;
constexpr int CM  = CB * CL;        // 43904 total tokens (= 128 windows * 343)
constexpr int POOL_CHUNKS = 86;     // ceil(21952/256)

typedef unsigned short ushortT;
typedef __attribute__((ext_vector_type(8))) short bf16x8;
typedef __attribute__((ext_vector_type(4))) float f32x4;

__device__ __forceinline__ int tt_to_pos(int tt, int& b) {
  int bw = tt / 343;
  int n  = tt - bw * 343;
  b = bw >> 6;
  int wi = bw & 63;
  int n0 = n / 49, r = n - n0 * 49;
  int n1 = r / 7,  n2 = r - n1 * 7;
  int h = (wi >> 4) * 7 + n0;
  int w = ((wi >> 2) & 3) * 7 + n1;
  int t = (wi & 3) * 7 + n2;
  return (h * 28 + w) * 28 + t;
}

__device__ __forceinline__ float gelu_exact(float x) {
  return 0.5f * x * (1.0f + erff(x * 0.70710678118654752f));
}

// fp32 -> bf16 round-to-nearest-even
__device__ __forceinline__ ushortT f2b(float x) {
  unsigned int u = __builtin_bit_cast(unsigned int, x);
  unsigned int r = (u + 0x7FFFu + ((u >> 16) & 1u)) >> 16;
  return (ushortT)r;
}

// ---------------- LayerNorm over C=192 -> bf16 out ----------------
__global__ __launch_bounds__(256) void ln_bf_kernel(const float* __restrict__ in,
                                                    const float* __restrict__ g,
                                                    const float* __restrict__ bb,
                                                    ushortT* __restrict__ out, int nrows) {
  int wave = threadIdx.x >> 6;
  int lane = threadIdx.x & 63;
  int row = blockIdx.x * 4 + wave;
  if (row >= nrows) return;
  const float* p = in + (size_t)row * CC;
  float v0 = p[lane], v1 = p[lane + 64], v2 = p[lane + 128];
  float s = v0 + v1 + v2;
  for (int o = 32; o; o >>= 1) s += __shfl_xor(s, o, 64);
  float mean = s * (1.0f / 192.0f);
  float d0 = v0 - mean, d1 = v1 - mean, d2 = v2 - mean;
  float qs = d0 * d0 + d1 * d1 + d2 * d2;
  for (int o = 32; o; o >>= 1) qs += __shfl_xor(qs, o, 64);
  float rs = rsqrtf(qs * (1.0f / 192.0f) + 1e-5f);
  ushortT* po = out + (size_t)row * CC;
  po[lane]       = f2b(d0 * rs * g[lane]       + bb[lane]);
  po[lane + 64]  = f2b(d1 * rs * g[lane + 64]  + bb[lane + 64]);
  po[lane + 128] = f2b(d2 * rs * g[lane + 128] + bb[lane + 128]);
}

// ---------------- weight prep: cast + conv re-layout, all in one ----------------
__global__ __launch_bounds__(256) void prep_kernel(const float* __restrict__ qkvw,
                                                   const float* __restrict__ projw,
                                                   const float* __restrict__ fc1w,
                                                   const float* __restrict__ fc2w,
                                                   const float* __restrict__ w1,
                                                   const float* __restrict__ w2,
                                                   ushortT* qkvwb, ushortT* projwb,
                                                   ushortT* fc1wb, ushortT* fc2wb,
                                                   ushortT* w1rb, ushortT* w2rb) {
  int i = blockIdx.x * 256 + threadIdx.x;
  if (i < 110592) { qkvwb[i] = f2b(qkvw[i]); return; }
  i -= 110592;
  if (i < 36864) { projwb[i] = f2b(projw[i]); return; }
  i -= 36864;
  if (i < 147456) { fc1wb[i] = f2b(fc1w[i]); return; }
  i -= 147456;
  if (i < 147456) { fc2wb[i] = f2b(fc2w[i]); return; }
  i -= 147456;
  if (i < 331776) {
    int o = i / 5184, r = i - o * 5184, tap = r / 192, c = r - tap * 192;
    w1rb[i] = f2b(w1[o * 5184 + c * 27 + tap]); return;
  }
  i -= 331776;
  if (i < 331776) {
    int o = i / 1728, r = i - o * 1728, tap = r / 64, c = r - tap * 64;
    w2rb[i] = f2b(w2[o * 1728 + c * 27 + tap]); return;
  }
}

// ---------------- MFMA GEMM core (64x64 tile, 4 waves, K-step 32) ----------------
#define GEMM_PROLOG \
  __shared__ ushortT As[64 * 40]; \
  __shared__ ushortT Bs[64 * 40]; \
  const int tid = threadIdx.x; \
  const int wave = tid >> 6, lane = tid & 63; \
  const int srow = tid >> 2, sk = (tid & 3) * 8; \
  const int fr = lane & 15, fk = (lane >> 4) * 8; \
  f32x4 zero_ = {0.f, 0.f, 0.f, 0.f}; \
  f32x4 acc[4]; \
  acc[0] = zero_; acc[1] = zero_; acc[2] = zero_; acc[3] = zero_;

#define GEMM_STEP(AV, BV) \
  *(uint4*)&As[srow * 40 + sk] = (AV); \
  *(uint4*)&Bs[srow * 40 + sk] = (BV); \
  __syncthreads(); \
  { bf16x8 af = *(const bf16x8*)&As[(wave * 16 + fr) * 40 + fk]; \
    _Pragma("unroll") \
    for (int c_ = 0; c_ < 4; ++c_) { \
      bf16x8 bfv = *(const bf16x8*)&Bs[(c_ * 16 + fr) * 40 + fk]; \
      acc[c_] = __builtin_amdgcn_mfma_f32_16x16x32_bf16(af, bfv, acc[c_], 0, 0, 0); \
    } } \
  __syncthreads();

// ---------------- Q projection ----------------
__global__ __launch_bounds__(256) void gemm_q_mf(const ushortT* __restrict__ xnb,
                                                 const ushortT* __restrict__ qkvwb,
                                                 const float* __restrict__ qkvb,
                                                 float* __restrict__ qout) {
  GEMM_PROLOG
  int bq;
  const int pos = tt_to_pos(blockIdx.x * 64 + srow, bq);
  const ushortT* arow = xnb + ((size_t)bq * CL + pos) * CC;
  const int jb = blockIdx.y * 64;
  const ushortT* brow = qkvwb + (size_t)(jb + srow) * CC;
  for (int k0 = 0; k0 < CC; k0 += 32) {
    uint4 avv = *(const uint4*)(arow + k0 + sk);
    uint4 bvv = *(const uint4*)(brow + k0 + sk);
    GEMM_STEP(avv, bvv)
  }
#pragma unroll
  for (int c = 0; c < 4; ++c) {
    int jj = jb + c * 16 + fr;
    int head = jj >> 5, d = jj & 31;
    float bias = qkvb[jj];
#pragma unroll
    for (int r = 0; r < 4; ++r) {
      int tt = blockIdx.x * 64 + wave * 16 + (lane >> 4) * 4 + r;
      int bw = tt / 343, n = tt - bw * 343;
      qout[(((size_t)bw * 6 + head) * 343 + n) * 32 + d] =
          (acc[c][r] + bias) * 0.17677669529663687f;
    }
  }
}

// ---------------- K,V projection ----------------
__global__ __launch_bounds__(256) void gemm_kv_mf(const ushortT* __restrict__ ynb,
                                                  const ushortT* __restrict__ qkvwb,
                                                  const float* __restrict__ qkvb,
                                                  float* __restrict__ kout,
                                                  float* __restrict__ vout) {
  GEMM_PROLOG
  int bq;
  const int pos = tt_to_pos(blockIdx.x * 64 + srow, bq);
  const ushortT* arow = ynb + ((size_t)bq * CL + pos) * CC;
  const int jb = blockIdx.y * 64;
  const ushortT* brow = qkvwb + (size_t)(192 + jb + srow) * CC;
  for (int k0 = 0; k0 < CC; k0 += 32) {
    uint4 avv = *(const uint4*)(arow + k0 + sk);
    uint4 bvv = *(const uint4*)(brow + k0 + sk);
    GEMM_STEP(avv, bvv)
  }
#pragma unroll
  for (int c = 0; c < 4; ++c) {
    int jj = jb + c * 16 + fr;
    float bias = qkvb[192 + jj];
    int jv = (jj < 192) ? jj : jj - 192;
    int head = jv >> 5, d = jv & 31;
    float* dst = (jj < 192) ? kout : vout;
#pragma unroll
    for (int r = 0; r < 4; ++r) {
      int tt = blockIdx.x * 64 + wave * 16 + (lane >> 4) * 4 + r;
      int bw = tt / 343, n = tt - bw * 343;
      dst[(((size_t)bw * 6 + head) * 343 + n) * 32 + d] = acc[c][r] + bias;
    }
  }
}

// ---------------- implicit-GEMM 3x3x3 conv, bf16 MFMA ----------------
// mode 1: GELU -> bf16 out; mode 0: fp32 out
__global__ __launch_bounds__(256) void conv_mf(const ushortT* __restrict__ src,
                                               const ushortT* __restrict__ wr,
                                               const float* __restrict__ bias,
                                               void* __restrict__ dst,
                                               int CIN, int COUT, int KT, int mode) {
  GEMM_PROLOG
  const int row = blockIdx.x * 64 + srow;
  const int b = row / CL, pos = row - b * CL;
  const int h = pos / 784, w = (pos / 28) % 28, t = pos % 28;
  const int jb = blockIdx.y * 64;
  const ushortT* brow = wr + (size_t)(jb + srow) * KT;
  int tap = 0, cbase = 0;
  for (int k0 = 0; k0 < KT; k0 += 32) {
    int dh = tap / 9 - 1, dw = (tap / 3) % 3 - 1, dt = tap % 3 - 1;
    int hh = h + dh, ww = w + dw, t2 = t + dt;
    bool ok = ((unsigned)hh < 28u) && ((unsigned)ww < 28u) && ((unsigned)t2 < 28u);
    uint4 avv = make_uint4(0u, 0u, 0u, 0u);
    if (ok)
      avv = *(const uint4*)(src + ((size_t)b * CL + (hh * 28 + ww) * 28 + t2) * CIN + cbase + sk);
    uint4 bvv = *(const uint4*)(brow + k0 + sk);   // FIX: was missing + sk
    GEMM_STEP(avv, bvv)
    cbase += 32;
    if (cbase == CIN) { cbase = 0; ++tap; }
  }
#pragma unroll
  for (int c = 0; c < 4; ++c) {
    int jj = jb + c * 16 + fr;
    float bs = bias[jj];
#pragma unroll
    for (int r = 0; r < 4; ++r) {
      int rr = blockIdx.x * 64 + wave * 16 + (lane >> 4) * 4 + r;
      float vv = acc[c][r] + bs;
      if (mode) ((ushortT*)dst)[(size_t)rr * COUT + jj] = f2b(gelu_exact(vv));
      else      ((float*)dst)[(size_t)rr * COUT + jj] = vv;
    }
  }
}

// ---------------- spatial mean partial sums ----------------
__global__ __launch_bounds__(192) void pool1_kernel(const float* __restrict__ h2,
                                                    float* __restrict__ part) {
  int c = threadIdx.x;
  int chunk = blockIdx.x;
  int b = blockIdx.y;
  int l0 = chunk * 256;
  int cnt = CL - l0; if (cnt > 256) cnt = 256;
  const float* p = h2 + ((size_t)b * CL + l0) * CC + c;
  float s = 0.0f;
  for (int i = 0; i < cnt; ++i) s += p[(size_t)i * CC];
  part[((size_t)b * POOL_CHUNKS + chunk) * CC + c] = s;
}

// ---------------- channel attention ----------------
__global__ __launch_bounds__(192) void ca_kernel(const float* __restrict__ part,
                                                 const float* __restrict__ ca1w,
                                                 const float* __restrict__ ca1b,
                                                 const float* __restrict__ ca2w,
                                                 const float* __restrict__ ca2b,
                                                 float* __restrict__ av) {
  __shared__ float pl[192];
  __shared__ float hid[12];
  int c = threadIdx.x, b = blockIdx.x;
  float s = 0.0f;
  for (int ch = 0; ch < POOL_CHUNKS; ++ch) s += part[((size_t)b * POOL_CHUNKS + ch) * CC + c];
  pl[c] = s * (1.0f / (float)CL);
  __syncthreads();
  if (c < 12) {
    float t = ca1b[c];
    for (int i = 0; i < 192; ++i) t += ca1w[c * 192 + i] * pl[i];
    hid[c] = fmaxf(t, 0.0f);
  }
  __syncthreads();
  float t = ca2b[c];
#pragma unroll
  for (int j = 0; j < 12; ++j) t += ca2w[c * 12 + j] * hid[j];
  av[b * 192 + c] = 1.0f / (1.0f + __expf(-t));
}

// ---------------- fused window attention (unchanged; bf16 out) ----------------
__global__ __launch_bounds__(256) void attn_kernel(const float* __restrict__ q,
                                                   const float* __restrict__ k,
                                                   const float* __restrict__ v,
                                                   const float* __restrict__ rpb,
                                                   ushortT* __restrict__ aout) {
  __shared__ float kl[343][33];
  __shared__ float vl[343][32];
  __shared__ float ql[32][33];
  __shared__ float sc[32][344];
  __shared__ float rinv[32];
  const int tid = threadIdx.x;
  const int wh = blockIdx.x;              // bw*6 + head
  const int bw = wh / 6, head = wh - bw * 6;
  const int q0 = blockIdx.y * 32;
  const int nq = (343 - q0 < 32) ? (343 - q0) : 32;
  const float* kp = k + (size_t)wh * 343 * 32;
  const float* vp = v + (size_t)wh * 343 * 32;
  const float* qp = q + (size_t)wh * 343 * 32;
  for (int idx = tid; idx < 343 * 32; idx += 256) {
    int n = idx >> 5, d = idx & 31;
    kl[n][d] = kp[idx];
    vl[n][d] = vp[idx];
  }
  for (int idx = tid; idx < 32 * 32; idx += 256) {
    int n = idx >> 5, d = idx & 31;
    ql[n][d] = (q0 + n < 343) ? qp[(size_t)(q0 + n) * 32 + d] : 0.0f;
  }
  __syncthreads();
  for (int p = tid; p < 32 * 343; p += 256) {
    int qi = p / 343, kj = p - qi * 343;
    float s = 0.0f;
#pragma unroll
    for (int d = 0; d < 32; ++d) s += ql[qi][d] * kl[kj][d];
    int ng = q0 + qi; if (ng > 342) ng = 342;
    int a0 = ng / 49, ra = ng - a0 * 49; int a1 = ra / 7, a2 = ra - a1 * 7;
    int b0 = kj / 49, rb = kj - b0 * 49; int b1 = rb / 7, b2 = rb - b1 * 7;
    int ridx = ((a0 - b0 + 6) * 13 + (a1 - b1 + 6)) * 13 + (a2 - b2 + 6);
    sc[qi][kj] = s + rpb[ridx * 6 + head];
  }
  __syncthreads();
  {
    int r = tid >> 3, l8 = tid & 7;
    float m = -1e30f;
    for (int j = l8; j < 343; j += 8) m = fmaxf(m, sc[r][j]);
    m = fmaxf(m, __shfl_xor(m, 1, 64));
    m = fmaxf(m, __shfl_xor(m, 2, 64));
    m = fmaxf(m, __shfl_xor(m, 4, 64));
    float sum = 0.0f;
    for (int j = l8; j < 343; j += 8) {
      float e = __expf(sc[r][j] - m);
      sc[r][j] = e;
      sum += e;
    }
    sum += __shfl_xor(sum, 1, 64);
    sum += __shfl_xor(sum, 2, 64);
    sum += __shfl_xor(sum, 4, 64);
    if (l8 == 0) rinv[r] = 1.0f / sum;
  }
  __syncthreads();
  {
    int qi = tid >> 3, d0 = (tid & 7) << 2;
    float o0 = 0, o1 = 0, o2 = 0, o3 = 0;
    for (int kj = 0; kj < 343; ++kj) {
      float pv = sc[qi][kj];
      o0 += pv * vl[kj][d0 + 0];
      o1 += pv * vl[kj][d0 + 1];
      o2 += pv * vl[kj][d0 + 2];
      o3 += pv * vl[kj][d0 + 3];
    }
    if (qi < nq) {
      float inv = rinv[qi];
      ushortT* op = aout + ((size_t)bw * 343 + q0 + qi) * CC + head * 32 + d0;
      op[0] = f2b(o0 * inv); op[1] = f2b(o1 * inv);
      op[2] = f2b(o2 * inv); op[3] = f2b(o3 * inv);
    }
  }
}

// ---------------- proj + window-reverse + 3-way residual ----------------
__global__ __launch_bounds__(256) void proj_mf(const ushortT* __restrict__ attnrb,
                                               const ushortT* __restrict__ projwb,
                                               const float* __restrict__ projb,
                                               const float* __restrict__ x0,
                                               const float* __restrict__ h2,
                                               const float* __restrict__ cav,
                                               float* __restrict__ xout) {
  GEMM_PROLOG
  const ushortT* arow = attnrb + (size_t)(blockIdx.x * 64 + srow) * CC;
  const int jb = blockIdx.y * 64;
  const ushortT* brow = projwb + (size_t)(jb + srow) * CC;
  for (int k0 = 0; k0 < CC; k0 += 32) {
    uint4 avv = *(const uint4*)(arow + k0 + sk);
    uint4 bvv = *(const uint4*)(brow + k0 + sk);
    GEMM_STEP(avv, bvv)
  }
#pragma unroll
  for (int r = 0; r < 4; ++r) {
    int tt = blockIdx.x * 64 + wave * 16 + (lane >> 4) * 4 + r;
    int bq;
    int pos = tt_to_pos(tt, bq);
    size_t base = ((size_t)bq * CL + pos) * CC;
#pragma unroll
    for (int c = 0; c < 4; ++c) {
      int jj = jb + c * 16 + fr;
      size_t addr = base + jj;
      xout[addr] = x0[addr] + acc[c][r] + projb[jj] + h2[addr] * cav[bq * 192 + jj];
    }
  }
}

// ---------------- MLP fc1 (+GELU) -> bf16 ----------------
__global__ __launch_bounds__(256) void fc1_mf(const ushortT* __restrict__ hlnb,
                                              const ushortT* __restrict__ fc1wb,
                                              const float* __restrict__ fc1b,
                                              ushortT* __restrict__ hidb) {
  GEMM_PROLOG
  const ushortT* arow = hlnb + (size_t)(blockIdx.x * 64 + srow) * CC;
  const int jb = blockIdx.y * 64;
  const ushortT* brow = fc1wb + (size_t)(jb + srow) * CC;
  for (int k0 = 0; k0 < CC; k0 += 32) {
    uint4 avv = *(const uint4*)(arow + k0 + sk);
    uint4 bvv = *(const uint4*)(brow + k0 + sk);
    GEMM_STEP(avv, bvv)
  }
#pragma unroll
  for (int c = 0; c < 4; ++c) {
    int jj = jb + c * 16 + fr;
    float bs = fc1b[jj];
#pragma unroll
    for (int r = 0; r < 4; ++r) {
      int rr = blockIdx.x * 64 + wave * 16 + (lane >> 4) * 4 + r;
      hidb[(size_t)rr * 768 + jj] = f2b(gelu_exact(acc[c][r] + bs));
    }
  }
}

// ---------------- MLP fc2 + final residual -> d_out ----------------
__global__ __launch_bounds__(256) void fc2_mf(const ushortT* __restrict__ hidb,
                                              const ushortT* __restrict__ fc2wb,
                                              const float* __restrict__ fc2b,
                                              const float* __restrict__ xout,
                                              float* __restrict__ out) {
  GEMM_PROLOG
  const ushortT* arow = hidb + (size_t)(blockIdx.x * 64 + srow) * 768;
  const int jb = blockIdx.y * 64;
  const ushortT* brow = fc2wb + (size_t)(jb + srow) * 768;
  for (int k0 = 0; k0 < 768; k0 += 32) {
    uint4 avv = *(const uint4*)(arow + k0 + sk);
    uint4 bvv = *(const uint4*)(brow + k0 + sk);
    GEMM_STEP(avv, bvv)
  }
#pragma unroll
  for (int c = 0; c < 4; ++c) {
    int jj = jb + c * 16 + fr;
    float bs = fc2b[jj];
#pragma unroll
    for (int r = 0; r < 4; ++r) {
      int rr = blockIdx.x * 64 + wave * 16 + (lane >> 4) * 4 + r;
      size_t addr = (size_t)rr * CC + jj;
      out[addr] = xout[addr] + acc[c][r] + bs;
    }
  }
}

// ---------------- launch ----------------
extern "C" void kernel_launch(void* const* d_in, const int* in_sizes, int n_in,
                              void* d_out, int out_size, void* d_ws, size_t ws_size,
                              hipStream_t stream) {
  const float* x     = (const float*)d_in[0];
  const float* y     = (const float*)d_in[1];
  const float* n1g   = (const float*)d_in[3];
  const float* n1b   = (const float*)d_in[4];
  const float* qkvw  = (const float*)d_in[5];
  const float* qkvb  = (const float*)d_in[6];
  const float* projw = (const float*)d_in[7];
  const float* projb = (const float*)d_in[8];
  const float* rpb   = (const float*)d_in[9];
  const float* n2g   = (const float*)d_in[10];
  const float* n2b   = (const float*)d_in[11];
  const float* fc1w  = (const float*)d_in[12];
  const float* fc1b  = (const float*)d_in[13];
  const float* fc2w  = (const float*)d_in[14];
  const float* fc2b  = (const float*)d_in[15];
  const float* w1    = (const float*)d_in[16];
  const float* b1    = (const float*)d_in[17];
  const float* w2    = (const float*)d_in[18];
  const float* b2    = (const float*)d_in[19];
  const float* ca1w  = (const float*)d_in[20];
  const float* ca1b  = (const float*)d_in[21];
  const float* ca2w  = (const float*)d_in[22];
  const float* ca2b  = (const float*)d_in[23];

  char* W = (char*)d_ws;
  float* out = (float*)d_out;

  ushortT* xnb  = (ushortT*)(W + 0);
  ushortT* ynb  = (ushortT*)(W + 16859136);
  float*   qb   = (float*)(W + 33718272);
  float*   kb   = (float*)(W + 67436544);
  float*   vb   = (float*)(W + 101154816);
  ushortT* h1b  = (ushortT*)(W + 134873088);
  float*   h2   = (float*)(W + 140492800);
  float*   xo   = (float*)(W + 174211072);
  char*    SM   = W + 207929344;
  ushortT* qkvwb = (ushortT*)(SM);
  ushortT* projwb = (ushortT*)(SM + 221184);
  ushortT* fc1wb = (ushortT*)(SM + 294912);
  ushortT* fc2wb = (ushortT*)(SM + 589824);
  ushortT* w1rb  = (ushortT*)(SM + 884736);
  ushortT* w2rb  = (ushortT*)(SM + 1548288);
  float*   av    = (float*)(SM + 2211840);
  float*   part  = (float*)(SM + 2213376);
  // aliases (stream-ordered lifetimes verified)
  ushortT* attnrb = xnb;                 // written by attn after conv1/gemm_q read xnb
  ushortT* hlnb   = ynb;                 // written by ln2 after gemm_kv read ynb
  ushortT* hidb   = (ushortT*)(W + 33718272);  // over q..k, after attn read them

  // 0. weight prep (cast + conv re-layout)
  prep_kernel<<<4320, 256, 0, stream>>>(qkvw, projw, fc1w, fc2w, w1, w2,
                                        qkvwb, projwb, fc1wb, fc2wb, w1rb, w2rb);

  // 1. LayerNorm1 -> bf16
  ln_bf_kernel<<<CM / 4, 256, 0, stream>>>(x, n1g, n1b, xnb, CM);
  ln_bf_kernel<<<CM / 4, 256, 0, stream>>>(y, n1g, n1b, ynb, CM);

  // 2. QKV projections (MFMA)
  gemm_q_mf<<<dim3(CM / 64, 3), 256, 0, stream>>>(xnb, qkvwb, qkvb, qb);
  gemm_kv_mf<<<dim3(CM / 64, 6), 256, 0, stream>>>(ynb, qkvwb, qkvb, kb, vb);

  // 3. CAB convs (implicit MFMA GEMM)
  conv_mf<<<dim3(CM / 64, 1), 256, 0, stream>>>(xnb, w1rb, b1, h1b, 192, 64, 5184, 1);
  conv_mf<<<dim3(CM / 64, 3), 256, 0, stream>>>(h1b, w2rb, b2, h2, 64, 192, 1728, 0);

  // 4. channel attention
  pool1_kernel<<<dim3(POOL_CHUNKS, CB), 192, 0, stream>>>(h2, part);
  ca_kernel<<<CB, 192, 0, stream>>>(part, ca1w, ca1b, ca2w, ca2b, av);

  // 5. fused window attention -> bf16 (aliases xnb)
  attn_kernel<<<dim3(128 * 6, 11), 256, 0, stream>>>(qb, kb, vb, rpb, attnrb);

  // 6. proj + window reverse + residual
  proj_mf<<<dim3(CM / 64, 3), 256, 0, stream>>>(attnrb, projwb, projb, x, h2, av, xo);

  // 7. LayerNorm2 -> bf16 (aliases ynb)
  ln_bf_kernel<<<CM / 4, 256, 0, stream>>>(xo, n2g, n2b, hlnb, CM);

  // 8. MLP (MFMA)
  fc1_mf<<<dim3(CM / 64, 12), 256, 0, stream>>>(hlnb, fc1wb, fc1b, hidb);
  fc2_mf<<<dim3(CM / 64, 3), 256, 0, stream>>>(hidb, fc2wb, fc2b, xo, out);
}

// Round 4
// 585.117 us; speedup vs baseline: 5.8278x; 2.4576x over previous
//
#include <hip/hip_runtime.h>
#include <math.h>

// ---------------- problem constants ----------------
constexpr int CB  = 2;
constexpr int CL  = 28 * 28 * 28;   // 21952
constexpr int CC  = 192;
constexpr int CM  = CB * CL;        // 43904 total tokens (= 128 windows * 343)
constexpr int POOL_CHUNKS = 86;     // ceil(21952/256)

typedef unsigned short ushortT;
typedef __attribute__((ext_vector_type(8))) short bf16x8;
typedef __attribute__((ext_vector_type(4))) float f32x4;

__device__ __forceinline__ int tt_to_pos(int tt, int& b) {
  int bw = tt / 343;
  int n  = tt - bw * 343;
  b = bw >> 6;
  int wi = bw & 63;
  int n0 = n / 49, r = n - n0 * 49;
  int n1 = r / 7,  n2 = r - n1 * 7;
  int h = (wi >> 4) * 7 + n0;
  int w = ((wi >> 2) & 3) * 7 + n1;
  int t = (wi & 3) * 7 + n2;
  return (h * 28 + w) * 28 + t;
}

__device__ __forceinline__ float gelu_exact(float x) {
  return 0.5f * x * (1.0f + erff(x * 0.70710678118654752f));
}

// fp32 -> bf16 round-to-nearest-even
__device__ __forceinline__ ushortT f2b(float x) {
  unsigned int u = __builtin_bit_cast(unsigned int, x);
  unsigned int r = (u + 0x7FFFu + ((u >> 16) & 1u)) >> 16;
  return (ushortT)r;
}

// ---------------- LayerNorm over C=192 -> bf16 out ----------------
__global__ __launch_bounds__(256) void ln_bf_kernel(const float* __restrict__ in,
                                                    const float* __restrict__ g,
                                                    const float* __restrict__ bb,
                                                    ushortT* __restrict__ out, int nrows) {
  int wave = threadIdx.x >> 6;
  int lane = threadIdx.x & 63;
  int row = blockIdx.x * 4 + wave;
  if (row >= nrows) return;
  const float* p = in + (size_t)row * CC;
  float v0 = p[lane], v1 = p[lane + 64], v2 = p[lane + 128];
  float s = v0 + v1 + v2;
  for (int o = 32; o; o >>= 1) s += __shfl_xor(s, o, 64);
  float mean = s * (1.0f / 192.0f);
  float d0 = v0 - mean, d1 = v1 - mean, d2 = v2 - mean;
  float qs = d0 * d0 + d1 * d1 + d2 * d2;
  for (int o = 32; o; o >>= 1) qs += __shfl_xor(qs, o, 64);
  float rs = rsqrtf(qs * (1.0f / 192.0f) + 1e-5f);
  ushortT* po = out + (size_t)row * CC;
  po[lane]       = f2b(d0 * rs * g[lane]       + bb[lane]);
  po[lane + 64]  = f2b(d1 * rs * g[lane + 64]  + bb[lane + 64]);
  po[lane + 128] = f2b(d2 * rs * g[lane + 128] + bb[lane + 128]);
}

// ---------------- weight prep: cast + conv re-layout ----------------
__global__ __launch_bounds__(256) void prep_kernel(const float* __restrict__ qkvw,
                                                   const float* __restrict__ projw,
                                                   const float* __restrict__ fc1w,
                                                   const float* __restrict__ fc2w,
                                                   const float* __restrict__ w1,
                                                   const float* __restrict__ w2,
                                                   ushortT* qkvwb, ushortT* projwb,
                                                   ushortT* fc1wb, ushortT* fc2wb,
                                                   ushortT* w1rb, ushortT* w2rb) {
  int i = blockIdx.x * 256 + threadIdx.x;
  if (i < 110592) { qkvwb[i] = f2b(qkvw[i]); return; }
  i -= 110592;
  if (i < 36864) { projwb[i] = f2b(projw[i]); return; }
  i -= 36864;
  if (i < 147456) { fc1wb[i] = f2b(fc1w[i]); return; }
  i -= 147456;
  if (i < 147456) { fc2wb[i] = f2b(fc2w[i]); return; }
  i -= 147456;
  if (i < 331776) {
    int o = i / 5184, r = i - o * 5184, tap = r / 192, c = r - tap * 192;
    w1rb[i] = f2b(w1[o * 5184 + c * 27 + tap]); return;
  }
  i -= 331776;
  if (i < 331776) {
    int o = i / 1728, r = i - o * 1728, tap = r / 64, c = r - tap * 64;
    w2rb[i] = f2b(w2[o * 1728 + c * 27 + tap]); return;
  }
}

// ---------------- rpb bias matrix precompute: rpbm[head][q][k] fp32 ----------------
__global__ __launch_bounds__(256) void rpbm_kernel(const float* __restrict__ rpb,
                                                   float* __restrict__ rpbm) {
  int idx = blockIdx.x * 256 + threadIdx.x;
  if (idx >= 6 * 343 * 343) return;
  int head = idx / 117649;
  int rem = idx - head * 117649;
  int q = rem / 343, k = rem - (rem / 343) * 343;
  int a0 = q / 49, ra = q - a0 * 49; int a1 = ra / 7, a2 = ra - a1 * 7;
  int b0 = k / 49, rb = k - b0 * 49; int b1 = rb / 7, b2 = rb - b1 * 7;
  int ridx = ((a0 - b0 + 6) * 13 + (a1 - b1 + 6)) * 13 + (a2 - b2 + 6);
  rpbm[idx] = rpb[ridx * 6 + head];
}

// ---------------- MFMA GEMM core (64x64 tile, 4 waves, K-step 32) ----------------
#define GEMM_PROLOG \
  __shared__ ushortT As[64 * 40]; \
  __shared__ ushortT Bs[64 * 40]; \
  const int tid = threadIdx.x; \
  const int wave = tid >> 6, lane = tid & 63; \
  const int srow = tid >> 2, sk = (tid & 3) * 8; \
  const int fr = lane & 15, fk = (lane >> 4) * 8; \
  f32x4 zero_ = {0.f, 0.f, 0.f, 0.f}; \
  f32x4 acc[4]; \
  acc[0] = zero_; acc[1] = zero_; acc[2] = zero_; acc[3] = zero_;

#define GEMM_STEP(AV, BV) \
  *(uint4*)&As[srow * 40 + sk] = (AV); \
  *(uint4*)&Bs[srow * 40 + sk] = (BV); \
  __syncthreads(); \
  { bf16x8 af = *(const bf16x8*)&As[(wave * 16 + fr) * 40 + fk]; \
    _Pragma("unroll") \
    for (int c_ = 0; c_ < 4; ++c_) { \
      bf16x8 bfv = *(const bf16x8*)&Bs[(c_ * 16 + fr) * 40 + fk]; \
      acc[c_] = __builtin_amdgcn_mfma_f32_16x16x32_bf16(af, bfv, acc[c_], 0, 0, 0); \
    } } \
  __syncthreads();

// ---------------- Q projection -> bf16 [wh][n][32], scaled ----------------
__global__ __launch_bounds__(256) void gemm_q_mf(const ushortT* __restrict__ xnb,
                                                 const ushortT* __restrict__ qkvwb,
                                                 const float* __restrict__ qkvb,
                                                 ushortT* __restrict__ qout) {
  GEMM_PROLOG
  int bq;
  const int pos = tt_to_pos(blockIdx.x * 64 + srow, bq);
  const ushortT* arow = xnb + ((size_t)bq * CL + pos) * CC;
  const int jb = blockIdx.y * 64;
  const ushortT* brow = qkvwb + (size_t)(jb + srow) * CC;
  for (int k0 = 0; k0 < CC; k0 += 32) {
    uint4 avv = *(const uint4*)(arow + k0 + sk);
    uint4 bvv = *(const uint4*)(brow + k0 + sk);
    GEMM_STEP(avv, bvv)
  }
#pragma unroll
  for (int c = 0; c < 4; ++c) {
    int jj = jb + c * 16 + fr;
    int head = jj >> 5, d = jj & 31;
    float bias = qkvb[jj];
#pragma unroll
    for (int r = 0; r < 4; ++r) {
      int tt = blockIdx.x * 64 + wave * 16 + (lane >> 4) * 4 + r;
      int bw = tt / 343, n = tt - bw * 343;
      qout[(((size_t)bw * 6 + head) * 343 + n) * 32 + d] =
          f2b((acc[c][r] + bias) * 0.17677669529663687f);
    }
  }
}

// ---------------- K,V projection -> bf16; K [wh][n][32], V transposed [wh][d][352] ----------------
__global__ __launch_bounds__(256) void gemm_kv_mf(const ushortT* __restrict__ ynb,
                                                  const ushortT* __restrict__ qkvwb,
                                                  const float* __restrict__ qkvb,
                                                  ushortT* __restrict__ kout,
                                                  ushortT* __restrict__ vout) {
  GEMM_PROLOG
  int bq;
  const int pos = tt_to_pos(blockIdx.x * 64 + srow, bq);
  const ushortT* arow = ynb + ((size_t)bq * CL + pos) * CC;
  const int jb = blockIdx.y * 64;
  const ushortT* brow = qkvwb + (size_t)(192 + jb + srow) * CC;
  for (int k0 = 0; k0 < CC; k0 += 32) {
    uint4 avv = *(const uint4*)(arow + k0 + sk);
    uint4 bvv = *(const uint4*)(brow + k0 + sk);
    GEMM_STEP(avv, bvv)
  }
#pragma unroll
  for (int c = 0; c < 4; ++c) {
    int jj = jb + c * 16 + fr;
    float bias = qkvb[192 + jj];
#pragma unroll
    for (int r = 0; r < 4; ++r) {
      int tt = blockIdx.x * 64 + wave * 16 + (lane >> 4) * 4 + r;
      int bw = tt / 343, n = tt - bw * 343;
      float val = acc[c][r] + bias;
      if (jj < 192) {
        int head = jj >> 5, d = jj & 31;
        kout[(((size_t)bw * 6 + head) * 343 + n) * 32 + d] = f2b(val);
      } else {
        int jv = jj - 192;
        int head = jv >> 5, d = jv & 31;
        vout[((size_t)bw * 6 + head) * 11264 + (size_t)d * 352 + n] = f2b(val);
      }
    }
  }
}

// ---------------- implicit-GEMM 3x3x3 conv, bf16 MFMA ----------------
__global__ __launch_bounds__(256) void conv_mf(const ushortT* __restrict__ src,
                                               const ushortT* __restrict__ wr,
                                               const float* __restrict__ bias,
                                               void* __restrict__ dst,
                                               int CIN, int COUT, int KT, int mode) {
  GEMM_PROLOG
  const int row = blockIdx.x * 64 + srow;
  const int b = row / CL, pos = row - b * CL;
  const int h = pos / 784, w = (pos / 28) % 28, t = pos % 28;
  const int jb = blockIdx.y * 64;
  const ushortT* brow = wr + (size_t)(jb + srow) * KT;
  int tap = 0, cbase = 0;
  for (int k0 = 0; k0 < KT; k0 += 32) {
    int dh = tap / 9 - 1, dw = (tap / 3) % 3 - 1, dt = tap % 3 - 1;
    int hh = h + dh, ww = w + dw, t2 = t + dt;
    bool ok = ((unsigned)hh < 28u) && ((unsigned)ww < 28u) && ((unsigned)t2 < 28u);
    uint4 avv = make_uint4(0u, 0u, 0u, 0u);
    if (ok)
      avv = *(const uint4*)(src + ((size_t)b * CL + (hh * 28 + ww) * 28 + t2) * CIN + cbase + sk);
    uint4 bvv = *(const uint4*)(brow + k0 + sk);
    GEMM_STEP(avv, bvv)
    cbase += 32;
    if (cbase == CIN) { cbase = 0; ++tap; }
  }
#pragma unroll
  for (int c = 0; c < 4; ++c) {
    int jj = jb + c * 16 + fr;
    float bs = bias[jj];
#pragma unroll
    for (int r = 0; r < 4; ++r) {
      int rr = blockIdx.x * 64 + wave * 16 + (lane >> 4) * 4 + r;
      float vv = acc[c][r] + bs;
      if (mode) ((ushortT*)dst)[(size_t)rr * COUT + jj] = f2b(gelu_exact(vv));
      else      ((float*)dst)[(size_t)rr * COUT + jj] = vv;
    }
  }
}

// ---------------- spatial mean partial sums ----------------
__global__ __launch_bounds__(192) void pool1_kernel(const float* __restrict__ h2,
                                                    float* __restrict__ part) {
  int c = threadIdx.x;
  int chunk = blockIdx.x;
  int b = blockIdx.y;
  int l0 = chunk * 256;
  int cnt = CL - l0; if (cnt > 256) cnt = 256;
  const float* p = h2 + ((size_t)b * CL + l0) * CC + c;
  float s = 0.0f;
  for (int i = 0; i < cnt; ++i) s += p[(size_t)i * CC];
  part[((size_t)b * POOL_CHUNKS + chunk) * CC + c] = s;
}

// ---------------- channel attention ----------------
__global__ __launch_bounds__(192) void ca_kernel(const float* __restrict__ part,
                                                 const float* __restrict__ ca1w,
                                                 const float* __restrict__ ca1b,
                                                 const float* __restrict__ ca2w,
                                                 const float* __restrict__ ca2b,
                                                 float* __restrict__ av) {
  __shared__ float pl[192];
  __shared__ float hid[12];
  int c = threadIdx.x, b = blockIdx.x;
  float s = 0.0f;
  for (int ch = 0; ch < POOL_CHUNKS; ++ch) s += part[((size_t)b * POOL_CHUNKS + ch) * CC + c];
  pl[c] = s * (1.0f / (float)CL);
  __syncthreads();
  if (c < 12) {
    float t = ca1b[c];
    for (int i = 0; i < 192; ++i) t += ca1w[c * 192 + i] * pl[i];
    hid[c] = fmaxf(t, 0.0f);
  }
  __syncthreads();
  float t = ca2b[c];
#pragma unroll
  for (int j = 0; j < 12; ++j) t += ca2w[c * 12 + j] * hid[j];
  av[b * 192 + c] = 1.0f / (1.0f + __expf(-t));
}

// ---------------- MFMA fused window attention ----------------
// one block per (window, head); 4 waves; q-tiles of 64 rows
constexpr int KP = 36;    // K lds pitch (bf16 elems)
constexpr int VP = 356;   // Vt / P lds pitch

__global__ __launch_bounds__(256) void attn_mf(const ushortT* __restrict__ qb,
                                               const ushortT* __restrict__ kb,
                                               const ushortT* __restrict__ vb,
                                               const float* __restrict__ rpbm,
                                               ushortT* __restrict__ aout) {
  __shared__ ushortT Kl[352 * KP];   // [key][d]
  __shared__ ushortT Vt[32 * VP];    // [d][key]
  __shared__ ushortT Pl[64 * VP];    // [q][key]
  __shared__ float rinvs[64];
  const int tid = threadIdx.x;
  const int wave = tid >> 6, lane = tid & 63;
  const int fr = lane & 15, g = lane >> 4, fk = g * 8;
  const int wh = blockIdx.x;
  const int bw = wh / 6, head = wh - bw * 6;
  const ushortT* kp = kb + (size_t)wh * 343 * 32;
  const ushortT* vp = vb + (size_t)wh * 11264;
  const ushortT* qp = qb + (size_t)wh * 343 * 32;
  const float* bp = rpbm + (size_t)head * 117649;

  // stage K (343 x 32 bf16, linear) -> Kl pitch KP
  for (int c = tid; c < 1372; c += 256) {
    int key = c >> 2, part = c & 3;
    *(uint4*)&Kl[key * KP + part * 8] = *(const uint4*)(kp + (size_t)c * 8);
  }
  // stage Vt (32 x 352 bf16, linear) -> Vt pitch VP
  for (int c = tid; c < 1408; c += 256) {
    int d = c / 44, p = c - d * 44;
    *(uint4*)&Vt[d * VP + p * 8] = *(const uint4*)(vp + (size_t)c * 8);
  }

  for (int q0 = 0; q0 < 343; q0 += 64) {
    __syncthreads();  // SYNC_A: staging visible (iter0) / prev PV reads done

    // Q A-fragment direct from global (rows clamped; invalid rows masked at store)
    int qrow = q0 + wave * 16 + fr; if (qrow > 342) qrow = 342;
    bf16x8 aq = *(const bf16x8*)(qp + (size_t)qrow * 32 + fk);

    const int qg0 = q0 + wave * 16 + g * 4;
    f32x4 sc[22];
#pragma unroll
    for (int t = 0; t < 22; ++t) {
      int kk = t * 16 + fr; if (kk > 342) kk = 342;
      f32x4 cini;
#pragma unroll
      for (int r = 0; r < 4; ++r) {
        int qq = qg0 + r; if (qq > 342) qq = 342;
        cini[r] = bp[(size_t)qq * 343 + kk];
      }
      bf16x8 bk = *(const bf16x8*)&Kl[(t * 16 + fr) * KP + fk];
      sc[t] = __builtin_amdgcn_mfma_f32_16x16x32_bf16(aq, bk, cini, 0, 0, 0);
    }
    // mask pad keys (tile 21 covers keys 336..351; fr>6 -> key>342). Overwrite kills NaN.
    if (fr > 6) { sc[21][0] = -1e30f; sc[21][1] = -1e30f; sc[21][2] = -1e30f; sc[21][3] = -1e30f; }

    // wave-parallel softmax: q = qg0+r, keys spread over (reg t, lane&15)
    float mx[4], sm[4];
#pragma unroll
    for (int r = 0; r < 4; ++r) {
      float m = sc[0][r];
#pragma unroll
      for (int t = 1; t < 22; ++t) m = fmaxf(m, sc[t][r]);
      m = fmaxf(m, __shfl_xor(m, 1, 64));
      m = fmaxf(m, __shfl_xor(m, 2, 64));
      m = fmaxf(m, __shfl_xor(m, 4, 64));
      m = fmaxf(m, __shfl_xor(m, 8, 64));
      mx[r] = m;
      sm[r] = 0.0f;
    }
#pragma unroll
    for (int t = 0; t < 22; ++t) {
#pragma unroll
      for (int r = 0; r < 4; ++r) {
        float e = __expf(sc[t][r] - mx[r]);
        sm[r] += e;
        Pl[(wave * 16 + g * 4 + r) * VP + t * 16 + fr] = f2b(e);
      }
    }
#pragma unroll
    for (int r = 0; r < 4; ++r) {
      float s = sm[r];
      s += __shfl_xor(s, 1, 64); s += __shfl_xor(s, 2, 64);
      s += __shfl_xor(s, 4, 64); s += __shfl_xor(s, 8, 64);
      if (fr == 0) rinvs[wave * 16 + g * 4 + r] = 1.0f / s;
    }
    __syncthreads();  // SYNC_B: P + rinv visible

    // PV: o[q][d], K-dim = 352 keys (P pad = 0)
    f32x4 o0 = {0.f, 0.f, 0.f, 0.f}, o1 = {0.f, 0.f, 0.f, 0.f};
#pragma unroll
    for (int s = 0; s < 11; ++s) {
      bf16x8 ap = *(const bf16x8*)&Pl[(wave * 16 + fr) * VP + s * 32 + fk];
      bf16x8 bv0 = *(const bf16x8*)&Vt[fr * VP + s * 32 + fk];
      bf16x8 bv1 = *(const bf16x8*)&Vt[(16 + fr) * VP + s * 32 + fk];
      o0 = __builtin_amdgcn_mfma_f32_16x16x32_bf16(ap, bv0, o0, 0, 0, 0);
      o1 = __builtin_amdgcn_mfma_f32_16x16x32_bf16(ap, bv1, o1, 0, 0, 0);
    }
#pragma unroll
    for (int r = 0; r < 4; ++r) {
      int q = q0 + wave * 16 + g * 4 + r;
      if (q < 343) {
        float ri = rinvs[wave * 16 + g * 4 + r];
        size_t base = ((size_t)bw * 343 + q) * 192 + head * 32;
        aout[base + fr]      = f2b(o0[r] * ri);
        aout[base + 16 + fr] = f2b(o1[r] * ri);
      }
    }
  }
}

// ---------------- proj + window-reverse + 3-way residual ----------------
__global__ __launch_bounds__(256) void proj_mf(const ushortT* __restrict__ attnrb,
                                               const ushortT* __restrict__ projwb,
                                               const float* __restrict__ projb,
                                               const float* __restrict__ x0,
                                               const float* __restrict__ h2,
                                               const float* __restrict__ cav,
                                               float* __restrict__ xout) {
  GEMM_PROLOG
  const ushortT* arow = attnrb + (size_t)(blockIdx.x * 64 + srow) * CC;
  const int jb = blockIdx.y * 64;
  const ushortT* brow = projwb + (size_t)(jb + srow) * CC;
  for (int k0 = 0; k0 < CC; k0 += 32) {
    uint4 avv = *(const uint4*)(arow + k0 + sk);
    uint4 bvv = *(const uint4*)(brow + k0 + sk);
    GEMM_STEP(avv, bvv)
  }
#pragma unroll
  for (int r = 0; r < 4; ++r) {
    int tt = blockIdx.x * 64 + wave * 16 + (lane >> 4) * 4 + r;
    int bq;
    int pos = tt_to_pos(tt, bq);
    size_t base = ((size_t)bq * CL + pos) * CC;
#pragma unroll
    for (int c = 0; c < 4; ++c) {
      int jj = jb + c * 16 + fr;
      size_t addr = base + jj;
      xout[addr] = x0[addr] + acc[c][r] + projb[jj] + h2[addr] * cav[bq * 192 + jj];
    }
  }
}

// ---------------- MLP fc1 (+GELU) -> bf16 ----------------
__global__ __launch_bounds__(256) void fc1_mf(const ushortT* __restrict__ hlnb,
                                              const ushortT* __restrict__ fc1wb,
                                              const float* __restrict__ fc1b,
                                              ushortT* __restrict__ hidb) {
  GEMM_PROLOG
  const ushortT* arow = hlnb + (size_t)(blockIdx.x * 64 + srow) * CC;
  const int jb = blockIdx.y * 64;
  const ushortT* brow = fc1wb + (size_t)(jb + srow) * CC;
  for (int k0 = 0; k0 < CC; k0 += 32) {
    uint4 avv = *(const uint4*)(arow + k0 + sk);
    uint4 bvv = *(const uint4*)(brow + k0 + sk);
    GEMM_STEP(avv, bvv)
  }
#pragma unroll
  for (int c = 0; c < 4; ++c) {
    int jj = jb + c * 16 + fr;
    float bs = fc1b[jj];
#pragma unroll
    for (int r = 0; r < 4; ++r) {
      int rr = blockIdx.x * 64 + wave * 16 + (lane >> 4) * 4 + r;
      hidb[(size_t)rr * 768 + jj] = f2b(gelu_exact(acc[c][r] + bs));
    }
  }
}

// ---------------- MLP fc2 + final residual -> d_out ----------------
__global__ __launch_bounds__(256) void fc2_mf(const ushortT* __restrict__ hidb,
                                              const ushortT* __restrict__ fc2wb,
                                              const float* __restrict__ fc2b,
                                              const float* __restrict__ xout,
                                              float* __restrict__ out) {
  GEMM_PROLOG
  const ushortT* arow = hidb + (size_t)(blockIdx.x * 64 + srow) * 768;
  const int jb = blockIdx.y * 64;
  const ushortT* brow = fc2wb + (size_t)(jb + srow) * 768;
  for (int k0 = 0; k0 < 768; k0 += 32) {
    uint4 avv = *(const uint4*)(arow + k0 + sk);
    uint4 bvv = *(const uint4*)(brow + k0 + sk);
    GEMM_STEP(avv, bvv)
  }
#pragma unroll
  for (int c = 0; c < 4; ++c) {
    int jj = jb + c * 16 + fr;
    float bs = fc2b[jj];
#pragma unroll
    for (int r = 0; r < 4; ++r) {
      int rr = blockIdx.x * 64 + wave * 16 + (lane >> 4) * 4 + r;
      size_t addr = (size_t)rr * CC + jj;
      out[addr] = xout[addr] + acc[c][r] + bs;
    }
  }
}

// ---------------- launch ----------------
extern "C" void kernel_launch(void* const* d_in, const int* in_sizes, int n_in,
                              void* d_out, int out_size, void* d_ws, size_t ws_size,
                              hipStream_t stream) {
  const float* x     = (const float*)d_in[0];
  const float* y     = (const float*)d_in[1];
  const float* n1g   = (const float*)d_in[3];
  const float* n1b   = (const float*)d_in[4];
  const float* qkvw  = (const float*)d_in[5];
  const float* qkvb  = (const float*)d_in[6];
  const float* projw = (const float*)d_in[7];
  const float* projb = (const float*)d_in[8];
  const float* rpb   = (const float*)d_in[9];
  const float* n2g   = (const float*)d_in[10];
  const float* n2b   = (const float*)d_in[11];
  const float* fc1w  = (const float*)d_in[12];
  const float* fc1b  = (const float*)d_in[13];
  const float* fc2w  = (const float*)d_in[14];
  const float* fc2b  = (const float*)d_in[15];
  const float* w1    = (const float*)d_in[16];
  const float* b1    = (const float*)d_in[17];
  const float* w2    = (const float*)d_in[18];
  const float* b2    = (const float*)d_in[19];
  const float* ca1w  = (const float*)d_in[20];
  const float* ca1b  = (const float*)d_in[21];
  const float* ca2w  = (const float*)d_in[22];
  const float* ca2b  = (const float*)d_in[23];

  char* W = (char*)d_ws;
  float* out = (float*)d_out;

  ushortT* xnb  = (ushortT*)(W + 0);
  ushortT* ynb  = (ushortT*)(W + 16859136);
  ushortT* qbb  = (ushortT*)(W + 33718272);
  ushortT* kbb  = (ushortT*)(W + 50577408);
  ushortT* vbb  = (ushortT*)(W + 67436544);   // [wh][32][352] bf16
  ushortT* h1b  = (ushortT*)(W + 84738048);
  float*   h2   = (float*)(W + 90357760);
  float*   xo   = (float*)(W + 124076032);
  char*    SM   = W + 157794304;
  ushortT* qkvwb  = (ushortT*)(SM);
  ushortT* projwb = (ushortT*)(SM + 221184);
  ushortT* fc1wb  = (ushortT*)(SM + 294912);
  ushortT* fc2wb  = (ushortT*)(SM + 589824);
  ushortT* w1rb   = (ushortT*)(SM + 884736);
  ushortT* w2rb   = (ushortT*)(SM + 1548288);
  float*   rpbm   = (float*)(SM + 2211840);   // 6*343*343 fp32 = 2,823,576 B
  float*   av     = (float*)(SM + 5035520);
  float*   part   = (float*)(SM + 5037056);
  // aliases (stream-ordered lifetimes verified)
  ushortT* attnrb = xnb;                       // attn writes after conv1/gemm_q read xnb
  ushortT* hlnb   = ynb;                       // ln2 writes after gemm_kv read ynb
  ushortT* hidb   = (ushortT*)(W + 33718272);  // over q/k/v/h1 (+h2 head), all dead by fc1

  // 0. weight prep + bias matrix
  prep_kernel<<<4320, 256, 0, stream>>>(qkvw, projw, fc1w, fc2w, w1, w2,
                                        qkvwb, projwb, fc1wb, fc2wb, w1rb, w2rb);
  rpbm_kernel<<<2758, 256, 0, stream>>>(rpb, rpbm);

  // 1. LayerNorm1 -> bf16
  ln_bf_kernel<<<CM / 4, 256, 0, stream>>>(x, n1g, n1b, xnb, CM);
  ln_bf_kernel<<<CM / 4, 256, 0, stream>>>(y, n1g, n1b, ynb, CM);

  // 2. QKV projections (MFMA) -> bf16
  gemm_q_mf<<<dim3(CM / 64, 3), 256, 0, stream>>>(xnb, qkvwb, qkvb, qbb);
  gemm_kv_mf<<<dim3(CM / 64, 6), 256, 0, stream>>>(ynb, qkvwb, qkvb, kbb, vbb);

  // 3. CAB convs (implicit MFMA GEMM)
  conv_mf<<<dim3(CM / 64, 1), 256, 0, stream>>>(xnb, w1rb, b1, h1b, 192, 64, 5184, 1);
  conv_mf<<<dim3(CM / 64, 3), 256, 0, stream>>>(h1b, w2rb, b2, h2, 64, 192, 1728, 0);

  // 4. channel attention
  pool1_kernel<<<dim3(POOL_CHUNKS, CB), 192, 0, stream>>>(h2, part);
  ca_kernel<<<CB, 192, 0, stream>>>(part, ca1w, ca1b, ca2w, ca2b, av);

  // 5. MFMA fused window attention -> bf16 (aliases xnb)
  attn_mf<<<768, 256, 0, stream>>>(qbb, kbb, vbb, rpbm, attnrb);

  // 6. proj + window reverse + residual
  proj_mf<<<dim3(CM / 64, 3), 256, 0, stream>>>(attnrb, projwb, projb, x, h2, av, xo);

  // 7. LayerNorm2 -> bf16 (aliases ynb)
  ln_bf_kernel<<<CM / 4, 256, 0, stream>>>(xo, n2g, n2b, hlnb, CM);

  // 8. MLP (MFMA)
  fc1_mf<<<dim3(CM / 64, 12), 256, 0, stream>>>(hlnb, fc1wb, fc1b, hidb);
  fc2_mf<<<dim3(CM / 64, 3), 256, 0, stream>>>(hidb, fc2wb, fc2b, xo, out);
}

// Round 5
// 526.543 us; speedup vs baseline: 6.4761x; 1.1112x over previous
//
#include <hip/hip_runtime.h>
#include <math.h>

// ---------------- problem constants ----------------
constexpr int CB  = 2;
constexpr int CL  = 28 * 28 * 28;   // 21952
constexpr int CC  = 192;
constexpr int CM  = CB * CL;        // 43904 total tokens (= 128 windows * 343)
constexpr int POOL_CHUNKS = 86;     // ceil(21952/256)

typedef unsigned short ushortT;
typedef __attribute__((ext_vector_type(8))) short bf16x8;
typedef __attribute__((ext_vector_type(4))) float f32x4;

__device__ __forceinline__ int tt_to_pos(int tt, int& b) {
  int bw = tt / 343;
  int n  = tt - bw * 343;
  b = bw >> 6;
  int wi = bw & 63;
  int n0 = n / 49, r = n - n0 * 49;
  int n1 = r / 7,  n2 = r - n1 * 7;
  int h = (wi >> 4) * 7 + n0;
  int w = ((wi >> 2) & 3) * 7 + n1;
  int t = (wi & 3) * 7 + n2;
  return (h * 28 + w) * 28 + t;
}

__device__ __forceinline__ float gelu_exact(float x) {
  return 0.5f * x * (1.0f + erff(x * 0.70710678118654752f));
}

__device__ __forceinline__ ushortT f2b(float x) {
  unsigned int u = __builtin_bit_cast(unsigned int, x);
  unsigned int r = (u + 0x7FFFu + ((u >> 16) & 1u)) >> 16;
  return (ushortT)r;
}

// async global->LDS, 16B per lane; falls back to reg round-trip if unavailable
typedef __attribute__((address_space(3))) unsigned int lds_uint;
typedef const __attribute__((address_space(1))) unsigned int glb_uint;
__device__ __forceinline__ void stage16(const ushortT* g, ushortT* l) {
#if defined(__has_builtin) && __has_builtin(__builtin_amdgcn_global_load_lds)
  __builtin_amdgcn_global_load_lds((glb_uint*)g, (lds_uint*)l, 16, 0, 0);
#else
  *(uint4*)l = *(const uint4*)g;
#endif
}

// swizzled LDS fragment pointer: 128B rows, 16B chunks, chunk ^= row&7
__device__ __forceinline__ const bf16x8* ldsfrag(const ushortT* base, int row, int chunk) {
  return (const bf16x8*)((const char*)base + row * 128 + ((chunk ^ (row & 7)) << 4));
}

// ---------------- LayerNorm over C=192 -> bf16 out ----------------
__global__ __launch_bounds__(256) void ln_bf_kernel(const float* __restrict__ in,
                                                    const float* __restrict__ g,
                                                    const float* __restrict__ bb,
                                                    ushortT* __restrict__ out, int nrows) {
  int wave = threadIdx.x >> 6;
  int lane = threadIdx.x & 63;
  int row = blockIdx.x * 4 + wave;
  if (row >= nrows) return;
  const float* p = in + (size_t)row * CC;
  float v0 = p[lane], v1 = p[lane + 64], v2 = p[lane + 128];
  float s = v0 + v1 + v2;
  for (int o = 32; o; o >>= 1) s += __shfl_xor(s, o, 64);
  float mean = s * (1.0f / 192.0f);
  float d0 = v0 - mean, d1 = v1 - mean, d2 = v2 - mean;
  float qs = d0 * d0 + d1 * d1 + d2 * d2;
  for (int o = 32; o; o >>= 1) qs += __shfl_xor(qs, o, 64);
  float rs = rsqrtf(qs * (1.0f / 192.0f) + 1e-5f);
  ushortT* po = out + (size_t)row * CC;
  po[lane]       = f2b(d0 * rs * g[lane]       + bb[lane]);
  po[lane + 64]  = f2b(d1 * rs * g[lane + 64]  + bb[lane + 64]);
  po[lane + 128] = f2b(d2 * rs * g[lane + 128] + bb[lane + 128]);
}

// ---------------- weight prep: cast + conv re-layout ----------------
__global__ __launch_bounds__(256) void prep_kernel(const float* __restrict__ qkvw,
                                                   const float* __restrict__ projw,
                                                   const float* __restrict__ fc1w,
                                                   const float* __restrict__ fc2w,
                                                   const float* __restrict__ w1,
                                                   const float* __restrict__ w2,
                                                   ushortT* qkvwb, ushortT* projwb,
                                                   ushortT* fc1wb, ushortT* fc2wb,
                                                   ushortT* w1rb, ushortT* w2rb) {
  int i = blockIdx.x * 256 + threadIdx.x;
  if (i < 110592) { qkvwb[i] = f2b(qkvw[i]); return; }
  i -= 110592;
  if (i < 36864) { projwb[i] = f2b(projw[i]); return; }
  i -= 36864;
  if (i < 147456) { fc1wb[i] = f2b(fc1w[i]); return; }
  i -= 147456;
  if (i < 147456) { fc2wb[i] = f2b(fc2w[i]); return; }
  i -= 147456;
  if (i < 331776) {
    int o = i / 5184, r = i - o * 5184, tap = r / 192, c = r - tap * 192;
    w1rb[i] = f2b(w1[o * 5184 + c * 27 + tap]); return;
  }
  i -= 331776;
  if (i < 331776) {
    int o = i / 1728, r = i - o * 1728, tap = r / 64, c = r - tap * 64;
    w2rb[i] = f2b(w2[o * 1728 + c * 27 + tap]); return;
  }
}

// ---------------- rpb bias matrix precompute: rpbm[head][q][k] fp32 ----------------
__global__ __launch_bounds__(256) void rpbm_kernel(const float* __restrict__ rpb,
                                                   float* __restrict__ rpbm) {
  int idx = blockIdx.x * 256 + threadIdx.x;
  if (idx >= 6 * 343 * 343) return;
  int head = idx / 117649;
  int rem = idx - head * 117649;
  int q = rem / 343, k = rem - (rem / 343) * 343;
  int a0 = q / 49, ra = q - a0 * 49; int a1 = ra / 7, a2 = ra - a1 * 7;
  int b0 = k / 49, rb = k - b0 * 49; int b1 = rb / 7, b2 = rb - b1 * 7;
  int ridx = ((a0 - b0 + 6) * 13 + (a1 - b1 + 6)) * 13 + (a2 - b2 + 6);
  rpbm[idx] = rpb[ridx * 6 + head];
}

// ================= GEMM core v2: BM=64, BK=64, 4 waves (2x2) =================
// wave tile 32 x (NF*16); LDS: A[64][64], B[NF*32*... BN][64], swizzled chunks.

#define CORE_IDS \
  const int tid = threadIdx.x; \
  const int wave = tid >> 6, lane = tid & 63; \
  const int fr = lane & 15, g = lane >> 4; \
  const int wr = wave >> 1, wc = wave & 1;

#define ZERO_ACC(NF) \
  f32x4 acc[2][NF]; \
  _Pragma("unroll") \
  for (int m_ = 0; m_ < 2; ++m_) { \
    _Pragma("unroll") \
    for (int n_ = 0; n_ < NF; ++n_) acc[m_][n_] = (f32x4){0.f, 0.f, 0.f, 0.f}; \
  }

// A rows = bx*64+row of a row-major matrix BASE with leading dim LDA
#define SETUP_A_ROWMAJOR(BASE, LDA) \
  const ushortT* pa[2]; ushortT* la[2]; \
  _Pragma("unroll") \
  for (int i = 0; i < 2; ++i) { \
    int slot = i * 256 + tid; int row_ = slot >> 3; \
    int cc8 = ((slot & 7) ^ (row_ & 7)) * 8; \
    pa[i] = (BASE) + (size_t)(blockIdx.x * 64 + row_) * (LDA) + cc8; \
    la[i] = Asl + slot * 8; \
  }

// A rows = window-token tt = bx*64+row, gathered from spatial-order BASE
#define SETUP_A_WINDOWED(BASE) \
  const ushortT* pa[2]; ushortT* la[2]; \
  _Pragma("unroll") \
  for (int i = 0; i < 2; ++i) { \
    int slot = i * 256 + tid; int row_ = slot >> 3; \
    int cc8 = ((slot & 7) ^ (row_ & 7)) * 8; \
    int bq_; int pos_ = tt_to_pos(blockIdx.x * 64 + row_, bq_); \
    pa[i] = (BASE) + ((size_t)bq_ * CL + pos_) * CC + cc8; \
    la[i] = Asl + slot * 8; \
  }

#define SETUP_B(BASE, ROWOFF, LDB, NR) \
  const ushortT* pb[NR]; ushortT* lb[NR]; \
  _Pragma("unroll") \
  for (int i = 0; i < NR; ++i) { \
    int slot = i * 256 + tid; int row_ = slot >> 3; \
    int cc8 = ((slot & 7) ^ (row_ & 7)) * 8; \
    pb[i] = (BASE) + (size_t)((ROWOFF) + row_) * (LDB) + cc8; \
    lb[i] = Bsl + slot * 8; \
  }

#define STAGE_AB(NR) \
  _Pragma("unroll") \
  for (int i = 0; i < 2; ++i) { stage16(pa[i], la[i]); pa[i] += 64; } \
  _Pragma("unroll") \
  for (int i = 0; i < NR; ++i) { stage16(pb[i], lb[i]); pb[i] += 64; }

#define CORE_MFMA(NF) \
  __syncthreads(); \
  _Pragma("unroll") \
  for (int kk = 0; kk < 2; ++kk) { \
    bf16x8 a0 = *ldsfrag(Asl, wr * 32 + fr, kk * 4 + g); \
    bf16x8 a1 = *ldsfrag(Asl, wr * 32 + 16 + fr, kk * 4 + g); \
    _Pragma("unroll") \
    for (int n_ = 0; n_ < NF; ++n_) { \
      bf16x8 bn = *ldsfrag(Bsl, wc * (NF * 16) + n_ * 16 + fr, kk * 4 + g); \
      acc[0][n_] = __builtin_amdgcn_mfma_f32_16x16x32_bf16(a0, bn, acc[0][n_], 0, 0, 0); \
      acc[1][n_] = __builtin_amdgcn_mfma_f32_16x16x32_bf16(a1, bn, acc[1][n_], 0, 0, 0); \
    } \
  } \
  __syncthreads();

// ---------------- Q projection -> bf16 [wh][n][32], scaled ----------------
__global__ __launch_bounds__(256) void gemm_q_n(const ushortT* __restrict__ xnb,
                                                const ushortT* __restrict__ qkvwb,
                                                const float* __restrict__ qkvb,
                                                ushortT* __restrict__ qout) {
  __shared__ alignas(16) ushortT Asl[64 * 64];
  __shared__ alignas(16) ushortT Bsl[192 * 64];
  CORE_IDS
  ZERO_ACC(6)
  SETUP_A_WINDOWED(xnb)
  SETUP_B(qkvwb, 0, 192, 6)
  for (int ks = 0; ks < 3; ++ks) {
    STAGE_AB(6)
    CORE_MFMA(6)
  }
#pragma unroll
  for (int n = 0; n < 6; ++n) {
    int jj = wc * 96 + n * 16 + fr;
    int head = jj >> 5, d = jj & 31;
    float bias = qkvb[jj];
#pragma unroll
    for (int m = 0; m < 2; ++m)
#pragma unroll
      for (int r = 0; r < 4; ++r) {
        int tt = blockIdx.x * 64 + wr * 32 + m * 16 + g * 4 + r;
        int bw = tt / 343, nn = tt - bw * 343;
        qout[(((size_t)bw * 6 + head) * 343 + nn) * 32 + d] =
            f2b((acc[m][n][r] + bias) * 0.17677669529663687f);
      }
  }
}

// ---------------- K,V projection -> bf16; K [wh][n][32], V transposed [wh][d][352] ----------------
__global__ __launch_bounds__(256) void gemm_kv_n(const ushortT* __restrict__ ynb,
                                                 const ushortT* __restrict__ qkvwb,
                                                 const float* __restrict__ qkvb,
                                                 ushortT* __restrict__ kout,
                                                 ushortT* __restrict__ vout) {
  __shared__ alignas(16) ushortT Asl[64 * 64];
  __shared__ alignas(16) ushortT Bsl[192 * 64];
  CORE_IDS
  const int jb = blockIdx.y * 192;
  ZERO_ACC(6)
  SETUP_A_WINDOWED(ynb)
  SETUP_B(qkvwb, 192 + jb, 192, 6)
  for (int ks = 0; ks < 3; ++ks) {
    STAGE_AB(6)
    CORE_MFMA(6)
  }
#pragma unroll
  for (int n = 0; n < 6; ++n) {
    int jj = jb + wc * 96 + n * 16 + fr;
    float bias = qkvb[192 + jj];
#pragma unroll
    for (int m = 0; m < 2; ++m)
#pragma unroll
      for (int r = 0; r < 4; ++r) {
        int tt = blockIdx.x * 64 + wr * 32 + m * 16 + g * 4 + r;
        int bw = tt / 343, nn = tt - bw * 343;
        float val = acc[m][n][r] + bias;
        if (jj < 192) {
          int head = jj >> 5, d = jj & 31;
          kout[(((size_t)bw * 6 + head) * 343 + nn) * 32 + d] = f2b(val);
        } else {
          int jv = jj - 192;
          int head = jv >> 5, d = jv & 31;
          vout[((size_t)bw * 6 + head) * 11264 + (size_t)d * 352 + nn] = f2b(val);
        }
      }
  }
}

// ---------------- implicit-GEMM 3x3x3 conv (template) ----------------
template <int CIN, int NF, int MODE>
__global__ __launch_bounds__(256) void conv_core(const ushortT* __restrict__ src,
                                                 const ushortT* __restrict__ wrw,
                                                 const float* __restrict__ bias,
                                                 void* __restrict__ dst) {
  constexpr int COUT = NF * 32;
  constexpr int KT = 27 * CIN;
  constexpr int KN = KT / 64;
  constexpr int NR = COUT * 8 / 256;
  __shared__ alignas(16) ushortT Asl[64 * 64];
  __shared__ alignas(16) ushortT Bsl[COUT * 64];
  CORE_IDS
  ZERO_ACC(NF)
  // A rows: spatial decomposition, precomputed
  int cA8[2], bbq[2], hh[2], ww[2], tt[2];
  ushortT* la[2];
#pragma unroll
  for (int i = 0; i < 2; ++i) {
    int slot = i * 256 + tid; int row_ = slot >> 3;
    cA8[i] = ((slot & 7) ^ (row_ & 7)) * 8;
    int grow = blockIdx.x * 64 + row_;
    bbq[i] = grow / CL;
    int pos = grow - bbq[i] * CL;
    hh[i] = pos / 784; ww[i] = (pos / 28) % 28; tt[i] = pos % 28;
    la[i] = Asl + slot * 8;
  }
  SETUP_B(wrw, 0, KT, NR)
#pragma unroll 1
  for (int ks = 0; ks < KN; ++ks) {
    int tap, cb;
    if (CIN == 64) { tap = ks; cb = 0; }
    else           { tap = ks / 3; cb = (ks - tap * 3) * 64; }
    int dh = tap / 9 - 1, dw = (tap / 3) % 3 - 1, dt = tap % 3 - 1;
#pragma unroll
    for (int i = 0; i < 2; ++i) {
      int h2_ = hh[i] + dh, w2_ = ww[i] + dw, t2_ = tt[i] + dt;
      bool ok = ((unsigned)h2_ < 28u) && ((unsigned)w2_ < 28u) && ((unsigned)t2_ < 28u);
      uint4 v = make_uint4(0u, 0u, 0u, 0u);
      if (ok)
        v = *(const uint4*)(src + ((size_t)bbq[i] * CL + (h2_ * 28 + w2_) * 28 + t2_) * CIN + cb + cA8[i]);
      *(uint4*)la[i] = v;
    }
#pragma unroll
    for (int i = 0; i < NR; ++i) { stage16(pb[i], lb[i]); pb[i] += 64; }
    CORE_MFMA(NF)
  }
#pragma unroll
  for (int n = 0; n < NF; ++n) {
    int jj = wc * (NF * 16) + n * 16 + fr;
    float bs = bias[jj];
#pragma unroll
    for (int m = 0; m < 2; ++m)
#pragma unroll
      for (int r = 0; r < 4; ++r) {
        int grow = blockIdx.x * 64 + wr * 32 + m * 16 + g * 4 + r;
        float vv = acc[m][n][r] + bs;
        if (MODE) ((ushortT*)dst)[(size_t)grow * COUT + jj] = f2b(gelu_exact(vv));
        else      ((float*)dst)[(size_t)grow * COUT + jj] = vv;
      }
  }
}

// ---------------- spatial mean partial sums ----------------
__global__ __launch_bounds__(192) void pool1_kernel(const float* __restrict__ h2,
                                                    float* __restrict__ part) {
  int c = threadIdx.x;
  int chunk = blockIdx.x;
  int b = blockIdx.y;
  int l0 = chunk * 256;
  int cnt = CL - l0; if (cnt > 256) cnt = 256;
  const float* p = h2 + ((size_t)b * CL + l0) * CC + c;
  float s = 0.0f;
  for (int i = 0; i < cnt; ++i) s += p[(size_t)i * CC];
  part[((size_t)b * POOL_CHUNKS + chunk) * CC + c] = s;
}

// ---------------- channel attention ----------------
__global__ __launch_bounds__(192) void ca_kernel(const float* __restrict__ part,
                                                 const float* __restrict__ ca1w,
                                                 const float* __restrict__ ca1b,
                                                 const float* __restrict__ ca2w,
                                                 const float* __restrict__ ca2b,
                                                 float* __restrict__ av) {
  __shared__ float pl[192];
  __shared__ float hid[12];
  int c = threadIdx.x, b = blockIdx.x;
  float s = 0.0f;
  for (int ch = 0; ch < POOL_CHUNKS; ++ch) s += part[((size_t)b * POOL_CHUNKS + ch) * CC + c];
  pl[c] = s * (1.0f / (float)CL);
  __syncthreads();
  if (c < 12) {
    float t = ca1b[c];
    for (int i = 0; i < 192; ++i) t += ca1w[c * 192 + i] * pl[i];
    hid[c] = fmaxf(t, 0.0f);
  }
  __syncthreads();
  float t = ca2b[c];
#pragma unroll
  for (int j = 0; j < 12; ++j) t += ca2w[c * 12 + j] * hid[j];
  av[b * 192 + c] = 1.0f / (1.0f + __expf(-t));
}

// ---------------- MFMA fused window attention (unchanged from round 4) ----------------
constexpr int KP = 36;    // K lds pitch (bf16 elems)
constexpr int VP = 356;   // Vt / P lds pitch

__global__ __launch_bounds__(256) void attn_mf(const ushortT* __restrict__ qb,
                                               const ushortT* __restrict__ kb,
                                               const ushortT* __restrict__ vb,
                                               const float* __restrict__ rpbm,
                                               ushortT* __restrict__ aout) {
  __shared__ ushortT Kl[352 * KP];
  __shared__ ushortT Vt[32 * VP];
  __shared__ ushortT Pl[64 * VP];
  __shared__ float rinvs[64];
  const int tid = threadIdx.x;
  const int wave = tid >> 6, lane = tid & 63;
  const int fr = lane & 15, g = lane >> 4, fk = g * 8;
  const int wh = blockIdx.x;
  const int bw = wh / 6, head = wh - bw * 6;
  const ushortT* kp = kb + (size_t)wh * 343 * 32;
  const ushortT* vp = vb + (size_t)wh * 11264;
  const ushortT* qp = qb + (size_t)wh * 343 * 32;
  const float* bp = rpbm + (size_t)head * 117649;

  for (int c = tid; c < 1372; c += 256) {
    int key = c >> 2, part = c & 3;
    *(uint4*)&Kl[key * KP + part * 8] = *(const uint4*)(kp + (size_t)c * 8);
  }
  for (int c = tid; c < 1408; c += 256) {
    int d = c / 44, p = c - d * 44;
    *(uint4*)&Vt[d * VP + p * 8] = *(const uint4*)(vp + (size_t)c * 8);
  }

  for (int q0 = 0; q0 < 343; q0 += 64) {
    __syncthreads();

    int qrow = q0 + wave * 16 + fr; if (qrow > 342) qrow = 342;
    bf16x8 aq = *(const bf16x8*)(qp + (size_t)qrow * 32 + fk);

    const int qg0 = q0 + wave * 16 + g * 4;
    f32x4 sc[22];
#pragma unroll
    for (int t = 0; t < 22; ++t) {
      int kk = t * 16 + fr; if (kk > 342) kk = 342;
      f32x4 cini;
#pragma unroll
      for (int r = 0; r < 4; ++r) {
        int qq = qg0 + r; if (qq > 342) qq = 342;
        cini[r] = bp[(size_t)qq * 343 + kk];
      }
      bf16x8 bk = *(const bf16x8*)&Kl[(t * 16 + fr) * KP + fk];
      sc[t] = __builtin_amdgcn_mfma_f32_16x16x32_bf16(aq, bk, cini, 0, 0, 0);
    }
    if (fr > 6) { sc[21][0] = -1e30f; sc[21][1] = -1e30f; sc[21][2] = -1e30f; sc[21][3] = -1e30f; }

    float mx[4], sm[4];
#pragma unroll
    for (int r = 0; r < 4; ++r) {
      float m = sc[0][r];
#pragma unroll
      for (int t = 1; t < 22; ++t) m = fmaxf(m, sc[t][r]);
      m = fmaxf(m, __shfl_xor(m, 1, 64));
      m = fmaxf(m, __shfl_xor(m, 2, 64));
      m = fmaxf(m, __shfl_xor(m, 4, 64));
      m = fmaxf(m, __shfl_xor(m, 8, 64));
      mx[r] = m;
      sm[r] = 0.0f;
    }
#pragma unroll
    for (int t = 0; t < 22; ++t) {
#pragma unroll
      for (int r = 0; r < 4; ++r) {
        float e = __expf(sc[t][r] - mx[r]);
        sm[r] += e;
        Pl[(wave * 16 + g * 4 + r) * VP + t * 16 + fr] = f2b(e);
      }
    }
#pragma unroll
    for (int r = 0; r < 4; ++r) {
      float s = sm[r];
      s += __shfl_xor(s, 1, 64); s += __shfl_xor(s, 2, 64);
      s += __shfl_xor(s, 4, 64); s += __shfl_xor(s, 8, 64);
      if (fr == 0) rinvs[wave * 16 + g * 4 + r] = 1.0f / s;
    }
    __syncthreads();

    f32x4 o0 = {0.f, 0.f, 0.f, 0.f}, o1 = {0.f, 0.f, 0.f, 0.f};
#pragma unroll
    for (int s = 0; s < 11; ++s) {
      bf16x8 ap = *(const bf16x8*)&Pl[(wave * 16 + fr) * VP + s * 32 + fk];
      bf16x8 bv0 = *(const bf16x8*)&Vt[fr * VP + s * 32 + fk];
      bf16x8 bv1 = *(const bf16x8*)&Vt[(16 + fr) * VP + s * 32 + fk];
      o0 = __builtin_amdgcn_mfma_f32_16x16x32_bf16(ap, bv0, o0, 0, 0, 0);
      o1 = __builtin_amdgcn_mfma_f32_16x16x32_bf16(ap, bv1, o1, 0, 0, 0);
    }
#pragma unroll
    for (int r = 0; r < 4; ++r) {
      int q = q0 + wave * 16 + g * 4 + r;
      if (q < 343) {
        float ri = rinvs[wave * 16 + g * 4 + r];
        size_t base = ((size_t)bw * 343 + q) * 192 + head * 32;
        aout[base + fr]      = f2b(o0[r] * ri);
        aout[base + 16 + fr] = f2b(o1[r] * ri);
      }
    }
  }
}

// ---------------- proj + window-reverse + 3-way residual ----------------
__global__ __launch_bounds__(256) void proj_n(const ushortT* __restrict__ attnrb,
                                              const ushortT* __restrict__ projwb,
                                              const float* __restrict__ projb,
                                              const float* __restrict__ x0,
                                              const float* __restrict__ h2,
                                              const float* __restrict__ cav,
                                              float* __restrict__ xout) {
  __shared__ alignas(16) ushortT Asl[64 * 64];
  __shared__ alignas(16) ushortT Bsl[192 * 64];
  CORE_IDS
  ZERO_ACC(6)
  SETUP_A_ROWMAJOR(attnrb, CC)
  SETUP_B(projwb, 0, 192, 6)
  for (int ks = 0; ks < 3; ++ks) {
    STAGE_AB(6)
    CORE_MFMA(6)
  }
#pragma unroll
  for (int m = 0; m < 2; ++m)
#pragma unroll
    for (int r = 0; r < 4; ++r) {
      int tt = blockIdx.x * 64 + wr * 32 + m * 16 + g * 4 + r;
      int bq_;
      int pos_ = tt_to_pos(tt, bq_);
      size_t base = ((size_t)bq_ * CL + pos_) * CC;
#pragma unroll
      for (int n = 0; n < 6; ++n) {
        int jj = wc * 96 + n * 16 + fr;
        size_t addr = base + jj;
        xout[addr] = x0[addr] + acc[m][n][r] + projb[jj] + h2[addr] * cav[bq_ * 192 + jj];
      }
    }
}

// ---------------- MLP fc1 (+GELU) -> bf16 ----------------
__global__ __launch_bounds__(256) void fc1_n(const ushortT* __restrict__ hlnb,
                                             const ushortT* __restrict__ fc1wb,
                                             const float* __restrict__ fc1b,
                                             ushortT* __restrict__ hidb) {
  __shared__ alignas(16) ushortT Asl[64 * 64];
  __shared__ alignas(16) ushortT Bsl[192 * 64];
  CORE_IDS
  const int jb = blockIdx.y * 192;
  ZERO_ACC(6)
  SETUP_A_ROWMAJOR(hlnb, CC)
  SETUP_B(fc1wb, jb, 192, 6)
  for (int ks = 0; ks < 3; ++ks) {
    STAGE_AB(6)
    CORE_MFMA(6)
  }
#pragma unroll
  for (int n = 0; n < 6; ++n) {
    int jj = wc * 96 + n * 16 + fr;
    float bs = fc1b[jb + jj];
#pragma unroll
    for (int m = 0; m < 2; ++m)
#pragma unroll
      for (int r = 0; r < 4; ++r) {
        int grow = blockIdx.x * 64 + wr * 32 + m * 16 + g * 4 + r;
        hidb[(size_t)grow * 768 + jb + jj] = f2b(gelu_exact(acc[m][n][r] + bs));
      }
  }
}

// ---------------- MLP fc2 + final residual -> d_out ----------------
__global__ __launch_bounds__(256) void fc2_n(const ushortT* __restrict__ hidb,
                                             const ushortT* __restrict__ fc2wb,
                                             const float* __restrict__ fc2b,
                                             const float* __restrict__ xout,
                                             float* __restrict__ out) {
  __shared__ alignas(16) ushortT Asl[64 * 64];
  __shared__ alignas(16) ushortT Bsl[192 * 64];
  CORE_IDS
  ZERO_ACC(6)
  SETUP_A_ROWMAJOR(hidb, 768)
  SETUP_B(fc2wb, 0, 768, 6)
  for (int ks = 0; ks < 12; ++ks) {
    STAGE_AB(6)
    CORE_MFMA(6)
  }
#pragma unroll
  for (int n = 0; n < 6; ++n) {
    int jj = wc * 96 + n * 16 + fr;
    float bs = fc2b[jj];
#pragma unroll
    for (int m = 0; m < 2; ++m)
#pragma unroll
      for (int r = 0; r < 4; ++r) {
        int grow = blockIdx.x * 64 + wr * 32 + m * 16 + g * 4 + r;
        size_t addr = (size_t)grow * CC + jj;
        out[addr] = xout[addr] + acc[m][n][r] + bs;
      }
  }
}

// ---------------- launch ----------------
extern "C" void kernel_launch(void* const* d_in, const int* in_sizes, int n_in,
                              void* d_out, int out_size, void* d_ws, size_t ws_size,
                              hipStream_t stream) {
  const float* x     = (const float*)d_in[0];
  const float* y     = (const float*)d_in[1];
  const float* n1g   = (const float*)d_in[3];
  const float* n1b   = (const float*)d_in[4];
  const float* qkvw  = (const float*)d_in[5];
  const float* qkvb  = (const float*)d_in[6];
  const float* projw = (const float*)d_in[7];
  const float* projb = (const float*)d_in[8];
  const float* rpb   = (const float*)d_in[9];
  const float* n2g   = (const float*)d_in[10];
  const float* n2b   = (const float*)d_in[11];
  const float* fc1w  = (const float*)d_in[12];
  const float* fc1b  = (const float*)d_in[13];
  const float* fc2w  = (const float*)d_in[14];
  const float* fc2b  = (const float*)d_in[15];
  const float* w1    = (const float*)d_in[16];
  const float* b1    = (const float*)d_in[17];
  const float* w2    = (const float*)d_in[18];
  const float* b2    = (const float*)d_in[19];
  const float* ca1w  = (const float*)d_in[20];
  const float* ca1b  = (const float*)d_in[21];
  const float* ca2w  = (const float*)d_in[22];
  const float* ca2b  = (const float*)d_in[23];

  char* W = (char*)d_ws;
  float* out = (float*)d_out;

  ushortT* xnb  = (ushortT*)(W + 0);
  ushortT* ynb  = (ushortT*)(W + 16859136);
  ushortT* qbb  = (ushortT*)(W + 33718272);
  ushortT* kbb  = (ushortT*)(W + 50577408);
  ushortT* vbb  = (ushortT*)(W + 67436544);   // [wh][32][352] bf16
  ushortT* h1b  = (ushortT*)(W + 84738048);
  float*   h2   = (float*)(W + 90357760);
  float*   xo   = (float*)(W + 124076032);
  char*    SM   = W + 157794304;
  ushortT* qkvwb  = (ushortT*)(SM);
  ushortT* projwb = (ushortT*)(SM + 221184);
  ushortT* fc1wb  = (ushortT*)(SM + 294912);
  ushortT* fc2wb  = (ushortT*)(SM + 589824);
  ushortT* w1rb   = (ushortT*)(SM + 884736);
  ushortT* w2rb   = (ushortT*)(SM + 1548288);
  float*   rpbm   = (float*)(SM + 2211840);
  float*   av     = (float*)(SM + 5035520);
  float*   part   = (float*)(SM + 5037056);
  ushortT* attnrb = xnb;
  ushortT* hlnb   = ynb;
  ushortT* hidb   = (ushortT*)(W + 33718272);

  // 0. weight prep + bias matrix
  prep_kernel<<<4320, 256, 0, stream>>>(qkvw, projw, fc1w, fc2w, w1, w2,
                                        qkvwb, projwb, fc1wb, fc2wb, w1rb, w2rb);
  rpbm_kernel<<<2758, 256, 0, stream>>>(rpb, rpbm);

  // 1. LayerNorm1 -> bf16
  ln_bf_kernel<<<CM / 4, 256, 0, stream>>>(x, n1g, n1b, xnb, CM);
  ln_bf_kernel<<<CM / 4, 256, 0, stream>>>(y, n1g, n1b, ynb, CM);

  // 2. QKV projections (MFMA core v2)
  gemm_q_n<<<686, 256, 0, stream>>>(xnb, qkvwb, qkvb, qbb);
  gemm_kv_n<<<dim3(686, 2), 256, 0, stream>>>(ynb, qkvwb, qkvb, kbb, vbb);

  // 3. CAB convs (implicit MFMA GEMM core v2)
  conv_core<192, 2, 1><<<686, 256, 0, stream>>>(xnb, w1rb, b1, h1b);
  conv_core<64, 6, 0><<<686, 256, 0, stream>>>(h1b, w2rb, b2, h2);

  // 4. channel attention
  pool1_kernel<<<dim3(POOL_CHUNKS, CB), 192, 0, stream>>>(h2, part);
  ca_kernel<<<CB, 192, 0, stream>>>(part, ca1w, ca1b, ca2w, ca2b, av);

  // 5. MFMA fused window attention -> bf16 (aliases xnb)
  attn_mf<<<768, 256, 0, stream>>>(qbb, kbb, vbb, rpbm, attnrb);

  // 6. proj + window reverse + residual
  proj_n<<<686, 256, 0, stream>>>(attnrb, projwb, projb, x, h2, av, xo);

  // 7. LayerNorm2 -> bf16 (aliases ynb)
  ln_bf_kernel<<<CM / 4, 256, 0, stream>>>(xo, n2g, n2b, hlnb, CM);

  // 8. MLP (MFMA core v2)
  fc1_n<<<dim3(686, 4), 256, 0, stream>>>(hlnb, fc1wb, fc1b, hidb);
  fc2_n<<<686, 256, 0, stream>>>(hidb, fc2wb, fc2b, xo, out);
}

// Round 6
// 483.500 us; speedup vs baseline: 7.0527x; 1.0890x over previous
//
#include <hip/hip_runtime.h>
#include <math.h>

// ---------------- problem constants ----------------
constexpr int CB  = 2;
constexpr int CL  = 28 * 28 * 28;   // 21952
constexpr int CC  = 192;
constexpr int CM  = CB * CL;        // 43904 total tokens (= 128 windows * 343)
constexpr int POOL_CHUNKS = 86;     // ceil(21952/256)

typedef unsigned short ushortT;
typedef __attribute__((ext_vector_type(8))) short bf16x8;
typedef __attribute__((ext_vector_type(4))) float f32x4;

__device__ __forceinline__ int tt_to_pos(int tt, int& b) {
  int bw = tt / 343;
  int n  = tt - bw * 343;
  b = bw >> 6;
  int wi = bw & 63;
  int n0 = n / 49, r = n - n0 * 49;
  int n1 = r / 7,  n2 = r - n1 * 7;
  int h = (wi >> 4) * 7 + n0;
  int w = ((wi >> 2) & 3) * 7 + n1;
  int t = (wi & 3) * 7 + n2;
  return (h * 28 + w) * 28 + t;
}

__device__ __forceinline__ float gelu_exact(float x) {
  return 0.5f * x * (1.0f + erff(x * 0.70710678118654752f));
}

__device__ __forceinline__ ushortT f2b(float x) {
  unsigned int u = __builtin_bit_cast(unsigned int, x);
  unsigned int r = (u + 0x7FFFu + ((u >> 16) & 1u)) >> 16;
  return (ushortT)r;
}

// async global->LDS, 16B per lane
typedef __attribute__((address_space(3))) unsigned int lds_uint;
typedef const __attribute__((address_space(1))) unsigned int glb_uint;
__device__ __forceinline__ void stage16(const ushortT* g, ushortT* l) {
#if defined(__has_builtin) && __has_builtin(__builtin_amdgcn_global_load_lds)
  __builtin_amdgcn_global_load_lds((glb_uint*)g, (lds_uint*)l, 16, 0, 0);
#else
  *(uint4*)l = *(const uint4*)g;
#endif
}

// swizzled LDS fragment pointer: 128B rows, 16B chunks, chunk ^= row&7
__device__ __forceinline__ const bf16x8* ldsfrag(const ushortT* base, int row, int chunk) {
  return (const bf16x8*)((const char*)base + row * 128 + ((chunk ^ (row & 7)) << 4));
}

// ---------------- LayerNorm over C=192 -> bf16 out (dual-input variant) ----------------
__global__ __launch_bounds__(256) void ln_dual_kernel(const float* __restrict__ in0,
                                                      const float* __restrict__ in1,
                                                      const float* __restrict__ g,
                                                      const float* __restrict__ bb,
                                                      ushortT* __restrict__ out0,
                                                      ushortT* __restrict__ out1) {
  int wave = threadIdx.x >> 6;
  int lane = threadIdx.x & 63;
  int row = blockIdx.x * 4 + wave;
  const float* in = blockIdx.y ? in1 : in0;
  ushortT* out = blockIdx.y ? out1 : out0;
  const float* p = in + (size_t)row * CC;
  float v0 = p[lane], v1 = p[lane + 64], v2 = p[lane + 128];
  float s = v0 + v1 + v2;
  for (int o = 32; o; o >>= 1) s += __shfl_xor(s, o, 64);
  float mean = s * (1.0f / 192.0f);
  float d0 = v0 - mean, d1 = v1 - mean, d2 = v2 - mean;
  float qs = d0 * d0 + d1 * d1 + d2 * d2;
  for (int o = 32; o; o >>= 1) qs += __shfl_xor(qs, o, 64);
  float rs = rsqrtf(qs * (1.0f / 192.0f) + 1e-5f);
  ushortT* po = out + (size_t)row * CC;
  po[lane]       = f2b(d0 * rs * g[lane]       + bb[lane]);
  po[lane + 64]  = f2b(d1 * rs * g[lane + 64]  + bb[lane + 64]);
  po[lane + 128] = f2b(d2 * rs * g[lane + 128] + bb[lane + 128]);
}

__global__ __launch_bounds__(256) void ln_bf_kernel(const float* __restrict__ in,
                                                    const float* __restrict__ g,
                                                    const float* __restrict__ bb,
                                                    ushortT* __restrict__ out, int nrows) {
  int wave = threadIdx.x >> 6;
  int lane = threadIdx.x & 63;
  int row = blockIdx.x * 4 + wave;
  if (row >= nrows) return;
  const float* p = in + (size_t)row * CC;
  float v0 = p[lane], v1 = p[lane + 64], v2 = p[lane + 128];
  float s = v0 + v1 + v2;
  for (int o = 32; o; o >>= 1) s += __shfl_xor(s, o, 64);
  float mean = s * (1.0f / 192.0f);
  float d0 = v0 - mean, d1 = v1 - mean, d2 = v2 - mean;
  float qs = d0 * d0 + d1 * d1 + d2 * d2;
  for (int o = 32; o; o >>= 1) qs += __shfl_xor(qs, o, 64);
  float rs = rsqrtf(qs * (1.0f / 192.0f) + 1e-5f);
  ushortT* po = out + (size_t)row * CC;
  po[lane]       = f2b(d0 * rs * g[lane]       + bb[lane]);
  po[lane + 64]  = f2b(d1 * rs * g[lane + 64]  + bb[lane + 64]);
  po[lane + 128] = f2b(d2 * rs * g[lane + 128] + bb[lane + 128]);
}

// ---------------- weight prep: cast + conv re-layout ----------------
__global__ __launch_bounds__(256) void prep_kernel(const float* __restrict__ qkvw,
                                                   const float* __restrict__ projw,
                                                   const float* __restrict__ fc1w,
                                                   const float* __restrict__ fc2w,
                                                   const float* __restrict__ w1,
                                                   const float* __restrict__ w2,
                                                   ushortT* qkvwb, ushortT* projwb,
                                                   ushortT* fc1wb, ushortT* fc2wb,
                                                   ushortT* w1rb, ushortT* w2rb) {
  int i = blockIdx.x * 256 + threadIdx.x;
  if (i < 110592) { qkvwb[i] = f2b(qkvw[i]); return; }
  i -= 110592;
  if (i < 36864) { projwb[i] = f2b(projw[i]); return; }
  i -= 36864;
  if (i < 147456) { fc1wb[i] = f2b(fc1w[i]); return; }
  i -= 147456;
  if (i < 147456) { fc2wb[i] = f2b(fc2w[i]); return; }
  i -= 147456;
  if (i < 331776) {
    int o = i / 5184, r = i - o * 5184, tap = r / 192, c = r - tap * 192;
    w1rb[i] = f2b(w1[o * 5184 + c * 27 + tap]); return;
  }
  i -= 331776;
  if (i < 331776) {
    int o = i / 1728, r = i - o * 1728, tap = r / 64, c = r - tap * 64;
    w2rb[i] = f2b(w2[o * 1728 + c * 27 + tap]); return;
  }
}

// ---------------- rpb in MFMA-C-fragment order: float4[head][qgrp][k] ----------------
// element r of the float4 = bias for q = qgrp*4+r, key = k. Pad (q>342 | k>342) = 0.
__global__ __launch_bounds__(256) void rpb4_kernel(const float* __restrict__ rpb,
                                                   float4* __restrict__ rpb4) {
  int idx = blockIdx.x * 256 + threadIdx.x;
  if (idx >= 6 * 88 * 352) return;
  int head = idx / (88 * 352);
  int rem = idx - head * 88 * 352;
  int qgrp = rem / 352, k = rem - qgrp * 352;
  float4 v = make_float4(0.f, 0.f, 0.f, 0.f);
  if (k < 343) {
    int b0 = k / 49, rb = k - b0 * 49; int b1 = rb / 7, b2 = rb - b1 * 7;
#pragma unroll
    for (int r = 0; r < 4; ++r) {
      int q = qgrp * 4 + r;
      if (q < 343) {
        int a0 = q / 49, ra = q - a0 * 49; int a1 = ra / 7, a2 = ra - a1 * 7;
        int ridx = ((a0 - b0 + 6) * 13 + (a1 - b1 + 6)) * 13 + (a2 - b2 + 6);
        (&v.x)[r] = rpb[ridx * 6 + head];
      }
    }
  }
  rpb4[idx] = v;
}

// ================= GEMM core v2: BM=64, BK=64, 4 waves (2x2) =================
#define CORE_IDS \
  const int tid = threadIdx.x; \
  const int wave = tid >> 6, lane = tid & 63; \
  const int fr = lane & 15, g = lane >> 4; \
  const int wr = wave >> 1, wc = wave & 1;

#define ZERO_ACC(NF) \
  f32x4 acc[2][NF]; \
  _Pragma("unroll") \
  for (int m_ = 0; m_ < 2; ++m_) { \
    _Pragma("unroll") \
    for (int n_ = 0; n_ < NF; ++n_) acc[m_][n_] = (f32x4){0.f, 0.f, 0.f, 0.f}; \
  }

#define SETUP_A_ROWMAJOR(BASE, LDA) \
  const ushortT* pa[2]; ushortT* la[2]; \
  _Pragma("unroll") \
  for (int i = 0; i < 2; ++i) { \
    int slot = i * 256 + tid; int row_ = slot >> 3; \
    int cc8 = ((slot & 7) ^ (row_ & 7)) * 8; \
    pa[i] = (BASE) + (size_t)(blockIdx.x * 64 + row_) * (LDA) + cc8; \
    la[i] = Asl + slot * 8; \
  }

#define SETUP_A_WINDOWED(BASE) \
  const ushortT* pa[2]; ushortT* la[2]; \
  _Pragma("unroll") \
  for (int i = 0; i < 2; ++i) { \
    int slot = i * 256 + tid; int row_ = slot >> 3; \
    int cc8 = ((slot & 7) ^ (row_ & 7)) * 8; \
    int bq_; int pos_ = tt_to_pos(blockIdx.x * 64 + row_, bq_); \
    pa[i] = (BASE) + ((size_t)bq_ * CL + pos_) * CC + cc8; \
    la[i] = Asl + slot * 8; \
  }

#define SETUP_B(BASE, ROWOFF, LDB, NR) \
  const ushortT* pb[NR]; ushortT* lb[NR]; \
  _Pragma("unroll") \
  for (int i = 0; i < NR; ++i) { \
    int slot = i * 256 + tid; int row_ = slot >> 3; \
    int cc8 = ((slot & 7) ^ (row_ & 7)) * 8; \
    pb[i] = (BASE) + (size_t)((ROWOFF) + row_) * (LDB) + cc8; \
    lb[i] = Bsl + slot * 8; \
  }

#define STAGE_AB(NR) \
  _Pragma("unroll") \
  for (int i = 0; i < 2; ++i) { stage16(pa[i], la[i]); pa[i] += 64; } \
  _Pragma("unroll") \
  for (int i = 0; i < NR; ++i) { stage16(pb[i], lb[i]); pb[i] += 64; }

#define CORE_MFMA(NF) \
  __syncthreads(); \
  _Pragma("unroll") \
  for (int kk = 0; kk < 2; ++kk) { \
    bf16x8 a0 = *ldsfrag(Asl, wr * 32 + fr, kk * 4 + g); \
    bf16x8 a1 = *ldsfrag(Asl, wr * 32 + 16 + fr, kk * 4 + g); \
    _Pragma("unroll") \
    for (int n_ = 0; n_ < NF; ++n_) { \
      bf16x8 bn = *ldsfrag(Bsl, wc * (NF * 16) + n_ * 16 + fr, kk * 4 + g); \
      acc[0][n_] = __builtin_amdgcn_mfma_f32_16x16x32_bf16(a0, bn, acc[0][n_], 0, 0, 0); \
      acc[1][n_] = __builtin_amdgcn_mfma_f32_16x16x32_bf16(a1, bn, acc[1][n_], 0, 0, 0); \
    } \
  } \
  __syncthreads();

// ---------------- Q projection -> bf16 [wh][n][32], scaled ----------------
__global__ __launch_bounds__(256) void gemm_q_n(const ushortT* __restrict__ xnb,
                                                const ushortT* __restrict__ qkvwb,
                                                const float* __restrict__ qkvb,
                                                ushortT* __restrict__ qout) {
  __shared__ alignas(16) ushortT Asl[64 * 64];
  __shared__ alignas(16) ushortT Bsl[192 * 64];
  CORE_IDS
  ZERO_ACC(6)
  SETUP_A_WINDOWED(xnb)
  SETUP_B(qkvwb, 0, 192, 6)
  for (int ks = 0; ks < 3; ++ks) {
    STAGE_AB(6)
    CORE_MFMA(6)
  }
#pragma unroll
  for (int n = 0; n < 6; ++n) {
    int jj = wc * 96 + n * 16 + fr;
    int head = jj >> 5, d = jj & 31;
    float bias = qkvb[jj];
#pragma unroll
    for (int m = 0; m < 2; ++m)
#pragma unroll
      for (int r = 0; r < 4; ++r) {
        int tt = blockIdx.x * 64 + wr * 32 + m * 16 + g * 4 + r;
        int bw = tt / 343, nn = tt - bw * 343;
        qout[(((size_t)bw * 6 + head) * 343 + nn) * 32 + d] =
            f2b((acc[m][n][r] + bias) * 0.17677669529663687f);
      }
  }
}

// ---------------- K,V projection -> bf16; K [wh][n][32], V transposed [wh][d][352] ----------------
__global__ __launch_bounds__(256) void gemm_kv_n(const ushortT* __restrict__ ynb,
                                                 const ushortT* __restrict__ qkvwb,
                                                 const float* __restrict__ qkvb,
                                                 ushortT* __restrict__ kout,
                                                 ushortT* __restrict__ vout) {
  __shared__ alignas(16) ushortT Asl[64 * 64];
  __shared__ alignas(16) ushortT Bsl[192 * 64];
  CORE_IDS
  const int jb = blockIdx.y * 192;
  ZERO_ACC(6)
  SETUP_A_WINDOWED(ynb)
  SETUP_B(qkvwb, 192 + jb, 192, 6)
  for (int ks = 0; ks < 3; ++ks) {
    STAGE_AB(6)
    CORE_MFMA(6)
  }
#pragma unroll
  for (int n = 0; n < 6; ++n) {
    int jj = jb + wc * 96 + n * 16 + fr;
    float bias = qkvb[192 + jj];
#pragma unroll
    for (int m = 0; m < 2; ++m)
#pragma unroll
      for (int r = 0; r < 4; ++r) {
        int tt = blockIdx.x * 64 + wr * 32 + m * 16 + g * 4 + r;
        int bw = tt / 343, nn = tt - bw * 343;
        float val = acc[m][n][r] + bias;
        if (jj < 192) {
          int head = jj >> 5, d = jj & 31;
          kout[(((size_t)bw * 6 + head) * 343 + nn) * 32 + d] = f2b(val);
        } else {
          int jv = jj - 192;
          int head = jv >> 5, d = jv & 31;
          vout[((size_t)bw * 6 + head) * 11264 + (size_t)d * 352 + nn] = f2b(val);
        }
      }
  }
}

// ---------------- implicit-GEMM 3x3x3 conv (template) ----------------
template <int CIN, int NF, int MODE>
__global__ __launch_bounds__(256) void conv_core(const ushortT* __restrict__ src,
                                                 const ushortT* __restrict__ wrw,
                                                 const float* __restrict__ bias,
                                                 void* __restrict__ dst) {
  constexpr int COUT = NF * 32;
  constexpr int KT = 27 * CIN;
  constexpr int KN = KT / 64;
  constexpr int NR = COUT * 8 / 256;
  __shared__ alignas(16) ushortT Asl[64 * 64];
  __shared__ alignas(16) ushortT Bsl[COUT * 64];
  CORE_IDS
  ZERO_ACC(NF)
  int cA8[2], bbq[2], hh[2], ww[2], tt[2];
  ushortT* la[2];
#pragma unroll
  for (int i = 0; i < 2; ++i) {
    int slot = i * 256 + tid; int row_ = slot >> 3;
    cA8[i] = ((slot & 7) ^ (row_ & 7)) * 8;
    int grow = blockIdx.x * 64 + row_;
    bbq[i] = grow / CL;
    int pos = grow - bbq[i] * CL;
    hh[i] = pos / 784; ww[i] = (pos / 28) % 28; tt[i] = pos % 28;
    la[i] = Asl + slot * 8;
  }
  SETUP_B(wrw, 0, KT, NR)
#pragma unroll 1
  for (int ks = 0; ks < KN; ++ks) {
    int tap, cb;
    if (CIN == 64) { tap = ks; cb = 0; }
    else           { tap = ks / 3; cb = (ks - tap * 3) * 64; }
    int dh = tap / 9 - 1, dw = (tap / 3) % 3 - 1, dt = tap % 3 - 1;
#pragma unroll
    for (int i = 0; i < 2; ++i) {
      int h2_ = hh[i] + dh, w2_ = ww[i] + dw, t2_ = tt[i] + dt;
      bool ok = ((unsigned)h2_ < 28u) && ((unsigned)w2_ < 28u) && ((unsigned)t2_ < 28u);
      uint4 v = make_uint4(0u, 0u, 0u, 0u);
      if (ok)
        v = *(const uint4*)(src + ((size_t)bbq[i] * CL + (h2_ * 28 + w2_) * 28 + t2_) * CIN + cb + cA8[i]);
      *(uint4*)la[i] = v;
    }
#pragma unroll
    for (int i = 0; i < NR; ++i) { stage16(pb[i], lb[i]); pb[i] += 64; }
    CORE_MFMA(NF)
  }
#pragma unroll
  for (int n = 0; n < NF; ++n) {
    int jj = wc * (NF * 16) + n * 16 + fr;
    float bs = bias[jj];
#pragma unroll
    for (int m = 0; m < 2; ++m)
#pragma unroll
      for (int r = 0; r < 4; ++r) {
        int grow = blockIdx.x * 64 + wr * 32 + m * 16 + g * 4 + r;
        float vv = acc[m][n][r] + bs;
        if (MODE) ((ushortT*)dst)[(size_t)grow * COUT + jj] = f2b(gelu_exact(vv));
        else      ((float*)dst)[(size_t)grow * COUT + jj] = vv;
      }
  }
}

// ---------------- spatial mean partial sums ----------------
__global__ __launch_bounds__(192) void pool1_kernel(const float* __restrict__ h2,
                                                    float* __restrict__ part) {
  int c = threadIdx.x;
  int chunk = blockIdx.x;
  int b = blockIdx.y;
  int l0 = chunk * 256;
  int cnt = CL - l0; if (cnt > 256) cnt = 256;
  const float* p = h2 + ((size_t)b * CL + l0) * CC + c;
  float s = 0.0f;
  for (int i = 0; i < cnt; ++i) s += p[(size_t)i * CC];
  part[((size_t)b * POOL_CHUNKS + chunk) * CC + c] = s;
}

// ---------------- channel attention ----------------
__global__ __launch_bounds__(192) void ca_kernel(const float* __restrict__ part,
                                                 const float* __restrict__ ca1w,
                                                 const float* __restrict__ ca1b,
                                                 const float* __restrict__ ca2w,
                                                 const float* __restrict__ ca2b,
                                                 float* __restrict__ av) {
  __shared__ float pl[192];
  __shared__ float hid[12];
  int c = threadIdx.x, b = blockIdx.x;
  float s = 0.0f;
  for (int ch = 0; ch < POOL_CHUNKS; ++ch) s += part[((size_t)b * POOL_CHUNKS + ch) * CC + c];
  pl[c] = s * (1.0f / (float)CL);
  __syncthreads();
  if (c < 12) {
    float t = ca1b[c];
    for (int i = 0; i < 192; ++i) t += ca1w[c * 192 + i] * pl[i];
    hid[c] = fmaxf(t, 0.0f);
  }
  __syncthreads();
  float t = ca2b[c];
#pragma unroll
  for (int j = 0; j < 12; ++j) t += ca2w[c * 12 + j] * hid[j];
  av[b * 192 + c] = 1.0f / (1.0f + __expf(-t));
}

// ---------------- MFMA fused window attention v3 ----------------
// grid (768, 2): block = (window*6+head, q-half). 4 waves. No intra-loop barriers:
// Pl rows and softmax state are strictly per-wave. LDS 72KB -> 2 blocks/CU.
constexpr int KP  = 36;    // K lds pitch (bf16 elems)
constexpr int VP  = 356;   // Vt pitch
constexpr int VP2 = 200;   // Pl pitch (two-phase PV: cols reused)

__global__ __launch_bounds__(256) void attn_v3(const ushortT* __restrict__ qb,
                                               const ushortT* __restrict__ kb,
                                               const ushortT* __restrict__ vb,
                                               const float* __restrict__ rpb4,
                                               ushortT* __restrict__ aout) {
  __shared__ ushortT Kl[352 * KP];   // 25,344 B
  __shared__ ushortT Vt[32 * VP];    // 22,784 B
  __shared__ ushortT Pl[64 * VP2];   // 25,600 B
  const int tid = threadIdx.x;
  const int wave = tid >> 6, lane = tid & 63;
  const int fr = lane & 15, g = lane >> 4, fk = g * 8;
  const int wh = blockIdx.x;
  const int bw = wh / 6, head = wh - bw * 6;
  const ushortT* kp = kb + (size_t)wh * 343 * 32;
  const ushortT* vp = vb + (size_t)wh * 11264;
  const ushortT* qp = qb + (size_t)wh * 343 * 32;
  const f32x4* bp4 = (const f32x4*)rpb4 + (size_t)head * 88 * 352;

  for (int c = tid; c < 1372; c += 256) {
    int key = c >> 2, part = c & 3;
    *(uint4*)&Kl[key * KP + part * 8] = *(const uint4*)(kp + (size_t)c * 8);
  }
  for (int c = tid; c < 1408; c += 256) {
    int d = c / 44, p = c - d * 44;
    *(uint4*)&Vt[d * VP + p * 8] = *(const uint4*)(vp + (size_t)c * 8);
  }
  __syncthreads();  // only barrier: K/V staging visible

  for (int qi = 0; qi < 3; ++qi) {
    const int q0 = (blockIdx.y * 3 + qi) * 64;

    int qrow = q0 + wave * 16 + fr; if (qrow > 342) qrow = 342;
    bf16x8 aq = *(const bf16x8*)(qp + (size_t)qrow * 32 + fk);

    const int qgrp = (q0 + wave * 16) / 4 + g;    // exact: q0, wave*16 divisible by 4
    f32x4 sc[22];
#pragma unroll
    for (int t = 0; t < 22; ++t) {
      f32x4 cini = bp4[(size_t)qgrp * 352 + t * 16 + fr];
      bf16x8 bk = *(const bf16x8*)&Kl[(t * 16 + fr) * KP + fk];
      sc[t] = __builtin_amdgcn_mfma_f32_16x16x32_bf16(aq, bk, cini, 0, 0, 0);
    }
    if (fr > 6) { sc[21][0] = -1e30f; sc[21][1] = -1e30f; sc[21][2] = -1e30f; sc[21][3] = -1e30f; }

    // wave-parallel softmax; running sums; e kept in sc
    float rinv[4];
#pragma unroll
    for (int r = 0; r < 4; ++r) {
      float m = sc[0][r];
#pragma unroll
      for (int t = 1; t < 22; ++t) m = fmaxf(m, sc[t][r]);
      m = fmaxf(m, __shfl_xor(m, 1, 64));
      m = fmaxf(m, __shfl_xor(m, 2, 64));
      m = fmaxf(m, __shfl_xor(m, 4, 64));
      m = fmaxf(m, __shfl_xor(m, 8, 64));
      float sum = 0.0f;
#pragma unroll
      for (int t = 0; t < 22; ++t) {
        float e = __expf(sc[t][r] - m);
        sc[t][r] = e;
        sum += e;
      }
      sum += __shfl_xor(sum, 1, 64); sum += __shfl_xor(sum, 2, 64);
      sum += __shfl_xor(sum, 4, 64); sum += __shfl_xor(sum, 8, 64);
      rinv[r] = 1.0f / sum;          // full sum present in every lane after butterfly
    }

    f32x4 o0 = {0.f, 0.f, 0.f, 0.f}, o1 = {0.f, 0.f, 0.f, 0.f};

    // ---- phase A: keys 0..191 (tiles 0..11) ----
#pragma unroll
    for (int t = 0; t < 12; ++t)
#pragma unroll
      for (int r = 0; r < 4; ++r)
        Pl[(wave * 16 + g * 4 + r) * VP2 + t * 16 + fr] = f2b(sc[t][r]);
    asm volatile("s_waitcnt lgkmcnt(0)" ::: "memory");   // writes done before reads
#pragma unroll
    for (int s = 0; s < 6; ++s) {
      bf16x8 ap  = *(const bf16x8*)&Pl[(wave * 16 + fr) * VP2 + s * 32 + fk];
      bf16x8 bv0 = *(const bf16x8*)&Vt[fr * VP + s * 32 + fk];
      bf16x8 bv1 = *(const bf16x8*)&Vt[(16 + fr) * VP + s * 32 + fk];
      o0 = __builtin_amdgcn_mfma_f32_16x16x32_bf16(ap, bv0, o0, 0, 0, 0);
      o1 = __builtin_amdgcn_mfma_f32_16x16x32_bf16(ap, bv1, o1, 0, 0, 0);
    }
    asm volatile("s_waitcnt lgkmcnt(0)" ::: "memory");   // reads done before overwrite

    // ---- phase B: keys 192..351 (tiles 12..21 -> cols 0..159) ----
#pragma unroll
    for (int t = 12; t < 22; ++t)
#pragma unroll
      for (int r = 0; r < 4; ++r)
        Pl[(wave * 16 + g * 4 + r) * VP2 + (t - 12) * 16 + fr] = f2b(sc[t][r]);
    asm volatile("s_waitcnt lgkmcnt(0)" ::: "memory");
#pragma unroll
    for (int s = 0; s < 5; ++s) {
      bf16x8 ap  = *(const bf16x8*)&Pl[(wave * 16 + fr) * VP2 + s * 32 + fk];
      bf16x8 bv0 = *(const bf16x8*)&Vt[fr * VP + 192 + s * 32 + fk];
      bf16x8 bv1 = *(const bf16x8*)&Vt[(16 + fr) * VP + 192 + s * 32 + fk];
      o0 = __builtin_amdgcn_mfma_f32_16x16x32_bf16(ap, bv0, o0, 0, 0, 0);
      o1 = __builtin_amdgcn_mfma_f32_16x16x32_bf16(ap, bv1, o1, 0, 0, 0);
    }
    asm volatile("s_waitcnt lgkmcnt(0)" ::: "memory");   // reads done before next qi writes

#pragma unroll
    for (int r = 0; r < 4; ++r) {
      int q = q0 + wave * 16 + g * 4 + r;
      if (q < 343) {
        float ri = rinv[r];
        size_t base = ((size_t)bw * 343 + q) * 192 + head * 32;
        aout[base + fr]      = f2b(o0[r] * ri);
        aout[base + 16 + fr] = f2b(o1[r] * ri);
      }
    }
  }
}

// ---------------- proj + window-reverse + 3-way residual ----------------
__global__ __launch_bounds__(256) void proj_n(const ushortT* __restrict__ attnrb,
                                              const ushortT* __restrict__ projwb,
                                              const float* __restrict__ projb,
                                              const float* __restrict__ x0,
                                              const float* __restrict__ h2,
                                              const float* __restrict__ cav,
                                              float* __restrict__ xout) {
  __shared__ alignas(16) ushortT Asl[64 * 64];
  __shared__ alignas(16) ushortT Bsl[192 * 64];
  CORE_IDS
  ZERO_ACC(6)
  SETUP_A_ROWMAJOR(attnrb, CC)
  SETUP_B(projwb, 0, 192, 6)
  for (int ks = 0; ks < 3; ++ks) {
    STAGE_AB(6)
    CORE_MFMA(6)
  }
#pragma unroll
  for (int m = 0; m < 2; ++m)
#pragma unroll
    for (int r = 0; r < 4; ++r) {
      int tt = blockIdx.x * 64 + wr * 32 + m * 16 + g * 4 + r;
      int bq_;
      int pos_ = tt_to_pos(tt, bq_);
      size_t base = ((size_t)bq_ * CL + pos_) * CC;
#pragma unroll
      for (int n = 0; n < 6; ++n) {
        int jj = wc * 96 + n * 16 + fr;
        size_t addr = base + jj;
        xout[addr] = x0[addr] + acc[m][n][r] + projb[jj] + h2[addr] * cav[bq_ * 192 + jj];
      }
    }
}

// ---------------- MLP fc1 (+GELU) -> bf16 ----------------
__global__ __launch_bounds__(256) void fc1_n(const ushortT* __restrict__ hlnb,
                                             const ushortT* __restrict__ fc1wb,
                                             const float* __restrict__ fc1b,
                                             ushortT* __restrict__ hidb) {
  __shared__ alignas(16) ushortT Asl[64 * 64];
  __shared__ alignas(16) ushortT Bsl[192 * 64];
  CORE_IDS
  const int jb = blockIdx.y * 192;
  ZERO_ACC(6)
  SETUP_A_ROWMAJOR(hlnb, CC)
  SETUP_B(fc1wb, jb, 192, 6)
  for (int ks = 0; ks < 3; ++ks) {
    STAGE_AB(6)
    CORE_MFMA(6)
  }
#pragma unroll
  for (int n = 0; n < 6; ++n) {
    int jj = wc * 96 + n * 16 + fr;
    float bs = fc1b[jb + jj];
#pragma unroll
    for (int m = 0; m < 2; ++m)
#pragma unroll
      for (int r = 0; r < 4; ++r) {
        int grow = blockIdx.x * 64 + wr * 32 + m * 16 + g * 4 + r;
        hidb[(size_t)grow * 768 + jb + jj] = f2b(gelu_exact(acc[m][n][r] + bs));
      }
  }
}

// ---------------- MLP fc2 + final residual -> d_out ----------------
__global__ __launch_bounds__(256) void fc2_n(const ushortT* __restrict__ hidb,
                                             const ushortT* __restrict__ fc2wb,
                                             const float* __restrict__ fc2b,
                                             const float* __restrict__ xout,
                                             float* __restrict__ out) {
  __shared__ alignas(16) ushortT Asl[64 * 64];
  __shared__ alignas(16) ushortT Bsl[192 * 64];
  CORE_IDS
  ZERO_ACC(6)
  SETUP_A_ROWMAJOR(hidb, 768)
  SETUP_B(fc2wb, 0, 768, 6)
  for (int ks = 0; ks < 12; ++ks) {
    STAGE_AB(6)
    CORE_MFMA(6)
  }
#pragma unroll
  for (int n = 0; n < 6; ++n) {
    int jj = wc * 96 + n * 16 + fr;
    float bs = fc2b[jj];
#pragma unroll
    for (int m = 0; m < 2; ++m)
#pragma unroll
      for (int r = 0; r < 4; ++r) {
        int grow = blockIdx.x * 64 + wr * 32 + m * 16 + g * 4 + r;
        size_t addr = (size_t)grow * CC + jj;
        out[addr] = xout[addr] + acc[m][n][r] + bs;
      }
  }
}

// ---------------- launch ----------------
extern "C" void kernel_launch(void* const* d_in, const int* in_sizes, int n_in,
                              void* d_out, int out_size, void* d_ws, size_t ws_size,
                              hipStream_t stream) {
  const float* x     = (const float*)d_in[0];
  const float* y     = (const float*)d_in[1];
  const float* n1g   = (const float*)d_in[3];
  const float* n1b   = (const float*)d_in[4];
  const float* qkvw  = (const float*)d_in[5];
  const float* qkvb  = (const float*)d_in[6];
  const float* projw = (const float*)d_in[7];
  const float* projb = (const float*)d_in[8];
  const float* rpb   = (const float*)d_in[9];
  const float* n2g   = (const float*)d_in[10];
  const float* n2b   = (const float*)d_in[11];
  const float* fc1w  = (const float*)d_in[12];
  const float* fc1b  = (const float*)d_in[13];
  const float* fc2w  = (const float*)d_in[14];
  const float* fc2b  = (const float*)d_in[15];
  const float* w1    = (const float*)d_in[16];
  const float* b1    = (const float*)d_in[17];
  const float* w2    = (const float*)d_in[18];
  const float* b2    = (const float*)d_in[19];
  const float* ca1w  = (const float*)d_in[20];
  const float* ca1b  = (const float*)d_in[21];
  const float* ca2w  = (const float*)d_in[22];
  const float* ca2b  = (const float*)d_in[23];

  char* W = (char*)d_ws;
  float* out = (float*)d_out;

  ushortT* xnb  = (ushortT*)(W + 0);
  ushortT* ynb  = (ushortT*)(W + 16859136);
  ushortT* qbb  = (ushortT*)(W + 33718272);
  ushortT* kbb  = (ushortT*)(W + 50577408);
  ushortT* vbb  = (ushortT*)(W + 67436544);   // [wh][32][352] bf16
  ushortT* h1b  = (ushortT*)(W + 84738048);
  float*   h2   = (float*)(W + 90357760);
  float*   xo   = (float*)(W + 124076032);
  char*    SM   = W + 157794304;
  ushortT* qkvwb  = (ushortT*)(SM);
  ushortT* projwb = (ushortT*)(SM + 221184);
  ushortT* fc1wb  = (ushortT*)(SM + 294912);
  ushortT* fc2wb  = (ushortT*)(SM + 589824);
  ushortT* w1rb   = (ushortT*)(SM + 884736);
  ushortT* w2rb   = (ushortT*)(SM + 1548288);
  float*   rpb4   = (float*)(SM + 2211840);   // 6*88*352 float4 = 2,973,696 B
  float*   av     = (float*)(SM + 5185536);
  float*   part   = (float*)(SM + 5187072);
  ushortT* attnrb = xnb;
  ushortT* hlnb   = ynb;
  ushortT* hidb   = (ushortT*)(W + 33718272);

  // 0. weight prep + rpb fragment table
  prep_kernel<<<4320, 256, 0, stream>>>(qkvw, projw, fc1w, fc2w, w1, w2,
                                        qkvwb, projwb, fc1wb, fc2wb, w1rb, w2rb);
  rpb4_kernel<<<726, 256, 0, stream>>>(rpb, (float4*)rpb4);

  // 1. LayerNorm1 on x and y (one dual launch)
  ln_dual_kernel<<<dim3(CM / 4, 2), 256, 0, stream>>>(x, y, n1g, n1b, xnb, ynb);

  // 2. QKV projections (MFMA core v2)
  gemm_q_n<<<686, 256, 0, stream>>>(xnb, qkvwb, qkvb, qbb);
  gemm_kv_n<<<dim3(686, 2), 256, 0, stream>>>(ynb, qkvwb, qkvb, kbb, vbb);

  // 3. CAB convs (implicit MFMA GEMM core v2)
  conv_core<192, 2, 1><<<686, 256, 0, stream>>>(xnb, w1rb, b1, h1b);
  conv_core<64, 6, 0><<<686, 256, 0, stream>>>(h1b, w2rb, b2, h2);

  // 4. channel attention
  pool1_kernel<<<dim3(POOL_CHUNKS, CB), 192, 0, stream>>>(h2, part);
  ca_kernel<<<CB, 192, 0, stream>>>(part, ca1w, ca1b, ca2w, ca2b, av);

  // 5. MFMA fused window attention v3 -> bf16 (aliases xnb)
  attn_v3<<<dim3(768, 2), 256, 0, stream>>>(qbb, kbb, vbb, rpb4, attnrb);

  // 6. proj + window reverse + residual
  proj_n<<<686, 256, 0, stream>>>(attnrb, projwb, projb, x, h2, av, xo);

  // 7. LayerNorm2 -> bf16 (aliases ynb)
  ln_bf_kernel<<<CM / 4, 256, 0, stream>>>(xo, n2g, n2b, hlnb, CM);

  // 8. MLP (MFMA core v2)
  fc1_n<<<dim3(686, 4), 256, 0, stream>>>(hlnb, fc1wb, fc1b, hidb);
  fc2_n<<<686, 256, 0, stream>>>(hidb, fc2wb, fc2b, xo, out);
}